// Round 1
// baseline (855.468 us; speedup 1.0000x reference)
//
#include <hip/hip_runtime.h>
#include <hip/hip_bf16.h>
#include <math.h>

#define NN   4096
#define KNB  10
#define ED   128
#define EFD  64
#define TD   64
#define DD   192     // E + T
#define KEYD 256     // E + EF + T
#define KDD  2560    // KEYD * KNB
#define HD   96      // DD / H
#define NH   2

// ---------------- build agg [N, 2560] ----------------
__global__ __launch_bounds__(256) void build_agg_kernel(
    const float* __restrict__ features, const float* __restrict__ edge_feats,
    const float* __restrict__ time_feats, const int* __restrict__ neighbors,
    float* __restrict__ agg)
{
    int n = blockIdx.x;
    int col = threadIdx.x; // 0..255 == KEYD
    #pragma unroll
    for (int k = 0; k < KNB; ++k) {
        int m = neighbors[n * KNB + k];
        float v;
        if (col < ED)            v = features[m * ED + col];
        else if (col < ED + EFD) v = edge_feats[(n * KNB + k) * EFD + (col - ED)];
        else                     v = time_feats[(n * KNB + k) * TD + (col - ED - EFD)];
        agg[n * KDD + k * KEYD + col] = v;
    }
}

// ---------------- gather x into h[:, 0:128] (h has ld = 320) ----------------
__global__ __launch_bounds__(256) void gather_x_kernel(
    const float* __restrict__ features, const int* __restrict__ node_idx,
    float* __restrict__ h)
{
    int i = blockIdx.x * 256 + threadIdx.x; // over N*ED
    int n = i / ED, c = i % ED;
    h[n * (DD + ED) + c] = features[node_idx[n] * ED + c];
}

// ---------------- generic fp32 GEMM: C = [relu](A @ B + bias) ----------------
// A [M, Kc] row-major lda; B [Kc, Nc] row-major ldb; C [M, Nc] ldc.
// BM=BN=64, BK=16, 256 threads, 4x4 micro-tile. All dims divide exactly.
template<bool RELU>
__global__ __launch_bounds__(256) void gemm_bias_kernel(
    const float* __restrict__ A, int lda,
    const float* __restrict__ B, int ldb,
    const float* __restrict__ bias,
    float* __restrict__ C, int ldc,
    int M, int Nc, int Kc)
{
    const int BM = 64, BN = 64, BK = 16, PAD = 4;
    __shared__ float As[BK][BM + PAD]; // As[k][m], stride 68
    __shared__ float Bs[BK][BN + PAD]; // Bs[k][n]
    int tid = threadIdx.x;
    int tx = tid % 16, ty = tid / 16;
    int m0 = blockIdx.y * BM;
    int n0 = blockIdx.x * BN;
    int a_m = tid / 4;            // 0..63
    int a_k = (tid % 4) * 4;      // 0,4,8,12
    int b_k = tid / 16;           // 0..15
    int b_n = (tid % 16) * 4;     // 0..60

    float acc[4][4] = {};
    for (int k0 = 0; k0 < Kc; k0 += BK) {
        float4 av = *(const float4*)&A[(size_t)(m0 + a_m) * lda + k0 + a_k];
        float4 bv = *(const float4*)&B[(size_t)(k0 + b_k) * ldb + n0 + b_n];
        As[a_k + 0][a_m] = av.x;
        As[a_k + 1][a_m] = av.y;
        As[a_k + 2][a_m] = av.z;
        As[a_k + 3][a_m] = av.w;
        *(float4*)&Bs[b_k][b_n] = bv;
        __syncthreads();
        #pragma unroll
        for (int k = 0; k < BK; ++k) {
            float4 a4 = *(const float4*)&As[k][ty * 4];
            float4 b4 = *(const float4*)&Bs[k][tx * 4];
            float aa[4] = {a4.x, a4.y, a4.z, a4.w};
            float bb[4] = {b4.x, b4.y, b4.z, b4.w};
            #pragma unroll
            for (int r = 0; r < 4; ++r)
                #pragma unroll
                for (int c = 0; c < 4; ++c)
                    acc[r][c] += aa[r] * bb[c];
        }
        __syncthreads();
    }
    #pragma unroll
    for (int r = 0; r < 4; ++r) {
        int row = m0 + ty * 4 + r;
        #pragma unroll
        for (int c = 0; c < 4; ++c) {
            int col = n0 + tx * 4 + c;
            float v = acc[r][c] + bias[col];
            if (RELU) v = fmaxf(v, 0.0f);
            C[(size_t)row * ldc + col] = v;
        }
    }
}

// ---------------- flash attention (fp32), per head ----------------
// q, kk, vv: [N, 192]; head = blockIdx.y selects 96-wide column slice.
// QB=32 queries/block, KB=64 keys per tile, 256 threads.
// Thread (ty=tid/16, tx=tid%16): S rows ty*2+{0,1}, S cols tx*4+{0..3},
//                                O cols tx*6+{0..5}.
__global__ __launch_bounds__(256) void attn_kernel(
    const float* __restrict__ q, const float* __restrict__ kk,
    const float* __restrict__ vv, float* __restrict__ o)
{
    const int QB = 32, KB = 64, HP = 97, PP = 65;
    __shared__ float Qs[QB * HP];
    __shared__ float Ks[KB * HP];
    __shared__ float Vs[KB * HP];
    __shared__ float Ps[QB * PP];
    int tid = threadIdx.x;
    int tx = tid % 16, ty = tid / 16;
    int hoff = blockIdx.y * HD;
    int q0 = blockIdx.x * QB;
    const float scale = 0.10206207261596577f; // 1/sqrt(96)

    for (int e = tid; e < QB * HD; e += 256) {
        int r = e / HD, c = e % HD;
        Qs[r * HP + c] = q[(size_t)(q0 + r) * DD + hoff + c];
    }

    float m_run[2] = {-1e30f, -1e30f};
    float l_run[2] = {0.0f, 0.0f};
    float acc[2][6] = {};

    for (int kb = 0; kb < NN; kb += KB) {
        for (int e = tid; e < KB * HD; e += 256) {
            int r = e / HD, c = e % HD;
            Ks[r * HP + c] = kk[(size_t)(kb + r) * DD + hoff + c];
            Vs[r * HP + c] = vv[(size_t)(kb + r) * DD + hoff + c];
        }
        __syncthreads();

        float s[2][4] = {};
        for (int d = 0; d < HD; ++d) {
            float qv0 = Qs[(ty * 2 + 0) * HP + d];
            float qv1 = Qs[(ty * 2 + 1) * HP + d];
            #pragma unroll
            for (int c = 0; c < 4; ++c) {
                float kv = Ks[(tx * 4 + c) * HP + d];
                s[0][c] += qv0 * kv;
                s[1][c] += qv1 * kv;
            }
        }

        #pragma unroll
        for (int r = 0; r < 2; ++r) {
            #pragma unroll
            for (int c = 0; c < 4; ++c) s[r][c] *= scale;
            float smax = fmaxf(fmaxf(s[r][0], s[r][1]), fmaxf(s[r][2], s[r][3]));
            #pragma unroll
            for (int off = 1; off < 16; off <<= 1)
                smax = fmaxf(smax, __shfl_xor(smax, off, 16));
            float m_new = fmaxf(m_run[r], smax);
            float p[4]; float rs = 0.0f;
            #pragma unroll
            for (int c = 0; c < 4; ++c) { p[c] = __expf(s[r][c] - m_new); rs += p[c]; }
            #pragma unroll
            for (int off = 1; off < 16; off <<= 1)
                rs += __shfl_xor(rs, off, 16);
            float corr = __expf(m_run[r] - m_new);
            l_run[r] = l_run[r] * corr + rs;
            m_run[r] = m_new;
            #pragma unroll
            for (int c = 0; c < 6; ++c) acc[r][c] *= corr;
            #pragma unroll
            for (int c = 0; c < 4; ++c)
                Ps[(ty * 2 + r) * PP + tx * 4 + c] = p[c];
        }
        // P rows are written and read by the same 16-lane group (same wave):
        // no barrier needed before PV.
        for (int j = 0; j < KB; ++j) {
            float p0 = Ps[(ty * 2 + 0) * PP + j];
            float p1 = Ps[(ty * 2 + 1) * PP + j];
            #pragma unroll
            for (int c = 0; c < 6; ++c) {
                float vval = Vs[j * HP + tx * 6 + c];
                acc[0][c] += p0 * vval;
                acc[1][c] += p1 * vval;
            }
        }
        __syncthreads();
    }

    #pragma unroll
    for (int r = 0; r < 2; ++r) {
        float inv = 1.0f / l_run[r];
        #pragma unroll
        for (int c = 0; c < 6; ++c)
            o[(size_t)(q0 + ty * 2 + r) * DD + hoff + tx * 6 + c] = acc[r][c] * inv;
    }
}

extern "C" void kernel_launch(void* const* d_in, const int* in_sizes, int n_in,
                              void* d_out, int out_size, void* d_ws, size_t ws_size,
                              hipStream_t stream) {
    const float* features   = (const float*)d_in[0];
    const float* edge_feats = (const float*)d_in[1];
    const float* time_feats = (const float*)d_in[2];
    const int*   neighbors  = (const int*)d_in[3];
    const int*   node_idx   = (const int*)d_in[4];
    const float* Wq = (const float*)d_in[5];
    const float* bq = (const float*)d_in[6];
    const float* Wk = (const float*)d_in[7];
    const float* bk = (const float*)d_in[8];
    const float* Wv = (const float*)d_in[9];
    const float* bv = (const float*)d_in[10];
    const float* Wo = (const float*)d_in[11];
    const float* bo = (const float*)d_in[12];
    const float* W1 = (const float*)d_in[13];
    const float* b1 = (const float*)d_in[14];
    const float* W2 = (const float*)d_in[15];
    const float* b2 = (const float*)d_in[16];
    float* out = (float*)d_out;

    float* ws  = (float*)d_ws;
    float* agg = ws;                       // N*KDD   = 10,485,760
    float* qb  = agg + (size_t)NN * KDD;   // N*DD
    float* kkb = qb  + (size_t)NN * DD;
    float* vvb = kkb + (size_t)NN * DD;
    float* ob  = vvb + (size_t)NN * DD;
    float* hb  = ob  + (size_t)NN * DD;    // N*(DD+ED) = N*320
    float* tb  = hb  + (size_t)NN * (DD + ED); // N*ED

    // 1) agg gather/concat
    build_agg_kernel<<<NN, 256, 0, stream>>>(features, edge_feats, time_feats,
                                             neighbors, agg);
    // 2) x -> h[:, 0:128]
    gather_x_kernel<<<(NN * ED) / 256, 256, 0, stream>>>(features, node_idx, hb);
    // 3) q = x @ Wq[0:128,:] + bq   (time-pad of q_in is zero)
    gemm_bias_kernel<false><<<dim3(DD / 64, NN / 64), 256, 0, stream>>>(
        hb, DD + ED, Wq, DD, bq, qb, DD, NN, DD, ED);
    // 4) kk = agg @ Wk + bk ; vv = agg @ Wv + bv
    gemm_bias_kernel<false><<<dim3(DD / 64, NN / 64), 256, 0, stream>>>(
        agg, KDD, Wk, DD, bk, kkb, DD, NN, DD, KDD);
    gemm_bias_kernel<false><<<dim3(DD / 64, NN / 64), 256, 0, stream>>>(
        agg, KDD, Wv, DD, bv, vvb, DD, NN, DD, KDD);
    // 5) attention per head -> ob [N, 192]
    attn_kernel<<<dim3(NN / 32, NH), 256, 0, stream>>>(qb, kkb, vvb, ob);
    // 6) attn_out = ob @ Wo + bo -> h[:, 128:320]
    gemm_bias_kernel<false><<<dim3(DD / 64, NN / 64), 256, 0, stream>>>(
        ob, DD, Wo, DD, bo, hb + ED, DD + ED, NN, DD, DD);
    // 7) t = relu(h @ W1 + b1)
    gemm_bias_kernel<true><<<dim3(ED / 64, NN / 64), 256, 0, stream>>>(
        hb, DD + ED, W1, ED, b1, tb, ED, NN, ED, DD + ED);
    // 8) out = t @ W2 + b2
    gemm_bias_kernel<false><<<dim3(ED / 64, NN / 64), 256, 0, stream>>>(
        tb, ED, W2, ED, b2, out, ED, NN, ED, ED);
}

// Round 3
// 195.398 us; speedup vs baseline: 4.3781x; 4.3781x over previous
//
#include <hip/hip_runtime.h>
#include <hip/hip_bf16.h>
#include <math.h>

#define NN   4096
#define KNB  10
#define ED   128
#define EFD  64
#define TD   64
#define DD   192     // E + T
#define KEYD 256     // E + EF + T
#define KDD  2560    // KEYD * KNB
#define HD   96      // DD / H
#define NH   2

typedef __attribute__((ext_vector_type(8))) short bf16x8;
typedef __attribute__((ext_vector_type(4))) float f32x4;

__device__ inline short f2bf(float f) {
    union { float f; unsigned int u; } c; c.f = f;
    unsigned int r = (c.u + 0x7FFFu + ((c.u >> 16) & 1u)) >> 16;
    return (short)r;
}

__device__ inline void gload_lds16(const void* g, void* lds) {
    __builtin_amdgcn_global_load_lds(
        (const __attribute__((address_space(1))) void*)g,
        (__attribute__((address_space(3))) void*)lds, 16, 0, 0);
}

// ---------------- build agg [N, 2560] in bf16 ----------------
__global__ __launch_bounds__(256) void build_agg_bf16(
    const float* __restrict__ features, const float* __restrict__ edge_feats,
    const float* __restrict__ time_feats, const int* __restrict__ neighbors,
    short* __restrict__ agg)
{
    int n = blockIdx.x;
    int col = threadIdx.x; // 0..255 == KEYD
    #pragma unroll
    for (int k = 0; k < KNB; ++k) {
        int m = neighbors[n * KNB + k];
        float v;
        if (col < ED)            v = features[m * ED + col];
        else if (col < ED + EFD) v = edge_feats[(n * KNB + k) * EFD + (col - ED)];
        else                     v = time_feats[(n * KNB + k) * TD + (col - ED - EFD)];
        agg[(size_t)n * KDD + k * KEYD + col] = f2bf(v);
    }
}

// ---------------- gather x into h[:, 0:128] (h has ld = 320) ----------------
__global__ __launch_bounds__(256) void gather_x_kernel(
    const float* __restrict__ features, const int* __restrict__ node_idx,
    float* __restrict__ h)
{
    int i = blockIdx.x * 256 + threadIdx.x; // over N*ED
    int n = i / ED, c = i % ED;
    h[n * (DD + ED) + c] = features[node_idx[n] * ED + c];
}

// ---------------- generic fp32 GEMM: C = [relu](A @ B + bias) ----------------
template<bool RELU>
__global__ __launch_bounds__(256) void gemm_bias_kernel(
    const float* __restrict__ A, int lda,
    const float* __restrict__ B, int ldb,
    const float* __restrict__ bias,
    float* __restrict__ C, int ldc,
    int M, int Nc, int Kc)
{
    const int BK = 16, PAD = 4;
    __shared__ float As[BK][64 + PAD];
    __shared__ float Bs[BK][64 + PAD];
    int tid = threadIdx.x;
    int tx = tid % 16, ty = tid / 16;
    int m0 = blockIdx.y * 64;
    int n0 = blockIdx.x * 64;
    int a_m = tid / 4;
    int a_k = (tid % 4) * 4;
    int b_k = tid / 16;
    int b_n = (tid % 16) * 4;

    float acc[4][4] = {};
    for (int k0 = 0; k0 < Kc; k0 += BK) {
        float4 av = *(const float4*)&A[(size_t)(m0 + a_m) * lda + k0 + a_k];
        float4 bv = *(const float4*)&B[(size_t)(k0 + b_k) * ldb + n0 + b_n];
        As[a_k + 0][a_m] = av.x;
        As[a_k + 1][a_m] = av.y;
        As[a_k + 2][a_m] = av.z;
        As[a_k + 3][a_m] = av.w;
        *(float4*)&Bs[b_k][b_n] = bv;
        __syncthreads();
        #pragma unroll
        for (int k = 0; k < BK; ++k) {
            float4 a4 = *(const float4*)&As[k][ty * 4];
            float4 b4 = *(const float4*)&Bs[k][tx * 4];
            float aa[4] = {a4.x, a4.y, a4.z, a4.w};
            float bb[4] = {b4.x, b4.y, b4.z, b4.w};
            #pragma unroll
            for (int r = 0; r < 4; ++r)
                #pragma unroll
                for (int c = 0; c < 4; ++c)
                    acc[r][c] += aa[r] * bb[c];
        }
        __syncthreads();
    }
    #pragma unroll
    for (int r = 0; r < 4; ++r) {
        int row = m0 + ty * 4 + r;
        #pragma unroll
        for (int c = 0; c < 4; ++c) {
            int col = n0 + tx * 4 + c;
            float v = acc[r][c] + bias[col];
            if (RELU) v = fmaxf(v, 0.0f);
            C[(size_t)row * ldc + col] = v;
        }
    }
}

// ---------------- fused K/V projection, bf16 MFMA ----------------
// C = agg[4096,2560] @ W[2560,192] + b.  nb<3 -> Wk -> kk bf16 [4096][192]
// nb>=3 -> Wv -> vvT bf16 [192][4096]  (transposed store for attention PV)
__global__ __launch_bounds__(256) void kv_gemm_mfma(
    const short* __restrict__ agg,
    const float* __restrict__ Wk, const float* __restrict__ bk,
    const float* __restrict__ Wv, const float* __restrict__ bv,
    short* __restrict__ kk, short* __restrict__ vvT)
{
    __shared__ short As[128 * 64];  // elem(m,k) at m*64 + ((k/8)^(m&7))*8 + k%8
    __shared__ short Bs[64 * 64];   // elem(k,n) at n*64 + ((k/8)^(n&7))*8 + k%8
    int tid = threadIdx.x, wid = tid >> 6, lane = tid & 63;
    int lx = lane & 15, lg = lane >> 4;
    int m0 = blockIdx.y * 128;
    int nb = blockIdx.x;
    bool isV = nb >= 3;
    const float* W = isV ? Wv : Wk;
    const float* bias = isV ? bv : bk;
    int n0 = (nb - (isV ? 3 : 0)) * 64;
    int wm0 = (wid >> 1) * 64, wn0 = (wid & 1) * 32;

    f32x4 acc[4][2] = {};

    for (int k0 = 0; k0 < KDD; k0 += 64) {
        // stage A: 16KB via global_load_lds (linear LDS dest, pre-swizzled src)
        #pragma unroll
        for (int it = 0; it < 4; ++it) {
            int idx = (wid * 4 + it) * 64 + lane;   // 16B-chunk index in tile
            int m = idx >> 3, s = idx & 7;
            int c = s ^ (m & 7);
            gload_lds16(agg + (size_t)(m0 + m) * KDD + k0 + c * 8,
                        &As[(wid * 4 + it) * 512]);
        }
        // stage B: fp32 -> bf16, transposed+swizzled (reg-staged)
        // 64 k-rows x 16 quads = 1024 quads, 256 threads x 4 iters
        #pragma unroll
        for (int jj = 0; jj < 4; ++jj) {
            int qidx = tid + jj * 256;              // 0..1023 quads
            int k = qidx >> 4, n4 = (qidx & 15) * 4;
            float4 w4 = *(const float4*)&W[(size_t)(k0 + k) * DD + n0 + n4];
            #pragma unroll
            for (int cc = 0; cc < 4; ++cc) {
                int n = n4 + cc;
                Bs[n * 64 + ((((k >> 3) ^ (n & 7)) << 3) | (k & 7))] = f2bf((&w4.x)[cc]);
            }
        }
        __syncthreads();
        #pragma unroll
        for (int ks = 0; ks < 2; ++ks) {
            bf16x8 af[4], bfr[2];
            #pragma unroll
            for (int mf = 0; mf < 4; ++mf) {
                int m = wm0 + mf * 16 + lx;
                af[mf] = *(const bf16x8*)&As[m * 64 + (((4 * ks + lg) ^ (m & 7)) << 3)];
            }
            #pragma unroll
            for (int nf = 0; nf < 2; ++nf) {
                int n = wn0 + nf * 16 + lx;
                bfr[nf] = *(const bf16x8*)&Bs[n * 64 + (((4 * ks + lg) ^ (n & 7)) << 3)];
            }
            #pragma unroll
            for (int mf = 0; mf < 4; ++mf)
                #pragma unroll
                for (int nf = 0; nf < 2; ++nf)
                    acc[mf][nf] = __builtin_amdgcn_mfma_f32_16x16x32_bf16(
                        af[mf], bfr[nf], acc[mf][nf], 0, 0, 0);
        }
        __syncthreads();
    }
    // epilogue: C/D layout row=(lane>>4)*4+reg, col=lane&15
    #pragma unroll
    for (int nf = 0; nf < 2; ++nf) {
        int ncol = n0 + wn0 + nf * 16 + lx;         // 0..191
        float bb = bias[ncol];
        #pragma unroll
        for (int mf = 0; mf < 4; ++mf) {
            int mrow = m0 + wm0 + mf * 16 + 4 * lg;
            if (!isV) {
                #pragma unroll
                for (int r = 0; r < 4; ++r)
                    kk[(size_t)(mrow + r) * DD + ncol] = f2bf(acc[mf][nf][r] + bb);
            } else {
                short4 s4;
                s4.x = f2bf(acc[mf][nf][0] + bb);
                s4.y = f2bf(acc[mf][nf][1] + bb);
                s4.z = f2bf(acc[mf][nf][2] + bb);
                s4.w = f2bf(acc[mf][nf][3] + bb);
                *(short4*)&vvT[(size_t)ncol * NN + mrow] = s4;
            }
        }
    }
}

// ---------------- flash attention, bf16 MFMA ----------------
// grid (N/64, heads, 2 key-splits); 4 waves, wave = 16 q-rows.
// K/V tiles (64 keys) double-buffered in LDS; P via per-wave padded LDS.
__global__ __launch_bounds__(256) void attn_mfma(
    const float* __restrict__ q,
    const short* __restrict__ kk,      // [4096][192] bf16
    const short* __restrict__ vvT,     // [192][4096] bf16
    float* __restrict__ opart,         // [2][4096][192] unnormalized
    float* __restrict__ ml)            // [2][2][4096][2]  {m, l}
{
    __shared__ short Ks[2][64 * 96];   // [key][d], 192B rows
    __shared__ short Vs[2][96 * 64];   // [d][key], chunk^=(d&7) swizzled
    __shared__ short Ps[4][16 * 72];   // per-wave P, padded rows
    int tid = threadIdx.x, wid = tid >> 6, lane = tid & 63;
    int lx = lane & 15, lg = lane >> 4;
    int h = blockIdx.y, split = blockIdx.z;
    int hoff = h * HD;
    int qb0 = blockIdx.x * 64 + wid * 16;
    const float scale = 0.10206207261596577f; // 1/sqrt(96)

    // Q fragments (A operand): lane -> Q[qb0+lx][hoff + ks*32 + lg*8 + i]
    bf16x8 qf[3];
    #pragma unroll
    for (int ks = 0; ks < 3; ++ks) {
        const float* src = q + (size_t)(qb0 + lx) * DD + hoff + ks * 32 + lg * 8;
        bf16x8 v;
        #pragma unroll
        for (int i = 0; i < 8; ++i) v[i] = f2bf(src[i]);
        qf[ks] = v;
    }

    auto stage = [&](int kb, int buf) {
        #pragma unroll
        for (int jj = 0; jj < 6; ++jj) {
            int j = wid * 6 + jj;
            if (j < 12) {                       // K tile: 64 rows x 12 chunks
                int idx = j * 64 + lane;
                int row = idx / 12, c = idx % 12;
                gload_lds16(kk + (size_t)(kb + row) * DD + hoff + c * 8,
                            &Ks[buf][j * 512]);
            } else {                            // V tile: 96 rows x 8 chunks
                int idx = (j - 12) * 64 + lane;
                int d = idx >> 3, s = idx & 7;
                int c = s ^ (d & 7);
                gload_lds16(vvT + (size_t)(hoff + d) * NN + kb + c * 8,
                            &Vs[buf][(j - 12) * 512]);
            }
        }
    };

    float m_run[4], l_run[4];
    #pragma unroll
    for (int r = 0; r < 4; ++r) { m_run[r] = -1e30f; l_run[r] = 0.f; }
    f32x4 accO[6] = {};
    short* myP = &Ps[wid][0];
    int kbase = split * 2048;

    stage(kbase, 0);

    for (int t = 0; t < 32; ++t) {
        int buf = t & 1;
        __syncthreads();  // staged loads drained (compiler vmcnt(0) before barrier)
        // ---- QK^T ----
        f32x4 sf[4];
        #pragma unroll
        for (int nf = 0; nf < 4; ++nf) sf[nf] = (f32x4){0.f, 0.f, 0.f, 0.f};
        #pragma unroll
        for (int ks = 0; ks < 3; ++ks) {
            #pragma unroll
            for (int nf = 0; nf < 4; ++nf) {
                bf16x8 kf = *(const bf16x8*)&Ks[buf][(nf * 16 + lx) * 96 + ks * 32 + lg * 8];
                sf[nf] = __builtin_amdgcn_mfma_f32_16x16x32_bf16(qf[ks], kf, sf[nf], 0, 0, 0);
            }
        }
        // ---- online softmax (row = 4*lg + r, cols lx + 16*nf) ----
        float pv[4][4];
        #pragma unroll
        for (int r = 0; r < 4; ++r) {
            float v0 = sf[0][r] * scale, v1 = sf[1][r] * scale;
            float v2 = sf[2][r] * scale, v3 = sf[3][r] * scale;
            float mx = fmaxf(fmaxf(v0, v1), fmaxf(v2, v3));
            mx = fmaxf(mx, __shfl_xor(mx, 1));
            mx = fmaxf(mx, __shfl_xor(mx, 2));
            mx = fmaxf(mx, __shfl_xor(mx, 4));
            mx = fmaxf(mx, __shfl_xor(mx, 8));
            float mnew = fmaxf(m_run[r], mx);
            float p0 = __expf(v0 - mnew), p1 = __expf(v1 - mnew);
            float p2 = __expf(v2 - mnew), p3 = __expf(v3 - mnew);
            float rs = p0 + p1 + p2 + p3;
            rs += __shfl_xor(rs, 1);
            rs += __shfl_xor(rs, 2);
            rs += __shfl_xor(rs, 4);
            rs += __shfl_xor(rs, 8);
            float corr = __expf(m_run[r] - mnew);
            l_run[r] = l_run[r] * corr + rs;
            m_run[r] = mnew;
            #pragma unroll
            for (int nf2 = 0; nf2 < 6; ++nf2) accO[nf2][r] *= corr;
            pv[r][0] = p0; pv[r][1] = p1; pv[r][2] = p2; pv[r][3] = p3;
        }
        // ---- write P to LDS (bf16) ----
        #pragma unroll
        for (int r = 0; r < 4; ++r)
            #pragma unroll
            for (int nf = 0; nf < 4; ++nf)
                myP[(4 * lg + r) * 72 + nf * 16 + lx] = f2bf(pv[r][nf]);
        __syncthreads();  // all waves' Ks/Vs[buf] reads done before restage
        // ---- prefetch next tile, then PV ----
        if (t < 31) stage(kbase + (t + 1) * 64, buf ^ 1);
        #pragma unroll
        for (int kf = 0; kf < 2; ++kf) {
            bf16x8 pf = *(const bf16x8*)&myP[lx * 72 + kf * 32 + lg * 8];
            #pragma unroll
            for (int nf2 = 0; nf2 < 6; ++nf2) {
                int d = nf2 * 16 + lx;
                bf16x8 vf = *(const bf16x8*)&Vs[buf][d * 64 + (((4 * kf + lg) ^ (d & 7)) << 3)];
                accO[nf2] = __builtin_amdgcn_mfma_f32_16x16x32_bf16(pf, vf, accO[nf2], 0, 0, 0);
            }
        }
    }

    // epilogue: unnormalized O + (m, l)
    float* op = opart + ((size_t)split * NN + qb0) * DD + hoff;
    #pragma unroll
    for (int nf2 = 0; nf2 < 6; ++nf2)
        #pragma unroll
        for (int r = 0; r < 4; ++r)
            op[(size_t)(4 * lg + r) * DD + nf2 * 16 + lx] = accO[nf2][r];
    float* mlp = ml + ((size_t)(split * NH + h) * NN + qb0) * 2;
    #pragma unroll
    for (int r = 0; r < 4; ++r)
        if (lx == r) {
            mlp[(4 * lg + r) * 2]     = m_run[r];
            mlp[(4 * lg + r) * 2 + 1] = l_run[r];
        }
}

// ---------------- merge the 2 key-splits ----------------
__global__ __launch_bounds__(256) void attn_combine(
    const float* __restrict__ opart, const float* __restrict__ ml,
    float* __restrict__ ob)
{
    int i = blockIdx.x * 256 + threadIdx.x;  // over 4096*192
    int row = i / DD, col = i % DD, h = col / HD;
    const float* ml0 = ml + ((size_t)(0 * NH + h) * NN + row) * 2;
    const float* ml1 = ml + ((size_t)(1 * NH + h) * NN + row) * 2;
    float mA = ml0[0], lA = ml0[1], mB = ml1[0], lB = ml1[1];
    float M = fmaxf(mA, mB);
    float wA = __expf(mA - M), wB = __expf(mB - M);
    float L = wA * lA + wB * lB;
    ob[i] = (opart[i] * wA + opart[(size_t)NN * DD + i] * wB) / L;
}

extern "C" void kernel_launch(void* const* d_in, const int* in_sizes, int n_in,
                              void* d_out, int out_size, void* d_ws, size_t ws_size,
                              hipStream_t stream) {
    const float* features   = (const float*)d_in[0];
    const float* edge_feats = (const float*)d_in[1];
    const float* time_feats = (const float*)d_in[2];
    const int*   neighbors  = (const int*)d_in[3];
    const int*   node_idx   = (const int*)d_in[4];
    const float* Wq = (const float*)d_in[5];
    const float* bq = (const float*)d_in[6];
    const float* Wk = (const float*)d_in[7];
    const float* bk = (const float*)d_in[8];
    const float* Wv = (const float*)d_in[9];
    const float* bv = (const float*)d_in[10];
    const float* Wo = (const float*)d_in[11];
    const float* bo = (const float*)d_in[12];
    const float* W1 = (const float*)d_in[13];
    const float* b1 = (const float*)d_in[14];
    const float* W2 = (const float*)d_in[15];
    const float* b2 = (const float*)d_in[16];
    float* out = (float*)d_out;

    char* w = (char*)d_ws;
    short* agg  = (short*)w;                    w += (size_t)NN * KDD * 2;      // 20.97 MB
    float* qb   = (float*)w;                    w += (size_t)NN * DD * 4;       // 3.15 MB
    short* kk   = (short*)w;                    w += (size_t)NN * DD * 2;       // 1.57 MB
    short* vvT  = (short*)w;                    w += (size_t)DD * NN * 2;       // 1.57 MB
    float* opart= (float*)w;                    w += (size_t)2 * NN * DD * 4;   // 6.29 MB
    float* ml   = (float*)w;                    w += (size_t)2 * NH * NN * 2 * 4;
    float* ob   = (float*)w;                    w += (size_t)NN * DD * 4;
    float* hb   = (float*)w;                    w += (size_t)NN * (DD + ED) * 4;
    float* tb   = (float*)w;                    w += (size_t)NN * ED * 4;

    build_agg_bf16<<<NN, 256, 0, stream>>>(features, edge_feats, time_feats,
                                           neighbors, agg);
    gather_x_kernel<<<(NN * ED) / 256, 256, 0, stream>>>(features, node_idx, hb);
    // q = x @ Wq[0:128,:] + bq  (time-pad of the query is zero)
    gemm_bias_kernel<false><<<dim3(DD / 64, NN / 64), 256, 0, stream>>>(
        hb, DD + ED, Wq, DD, bq, qb, DD, NN, DD, ED);
    kv_gemm_mfma<<<dim3(6, NN / 128), 256, 0, stream>>>(agg, Wk, bk, Wv, bv, kk, vvT);
    attn_mfma<<<dim3(NN / 64, NH, 2), 256, 0, stream>>>(qb, kk, vvT, opart, ml);
    attn_combine<<<(NN * DD) / 256, 256, 0, stream>>>(opart, ml, ob);
    gemm_bias_kernel<false><<<dim3(DD / 64, NN / 64), 256, 0, stream>>>(
        ob, DD, Wo, DD, bo, hb + ED, DD + ED, NN, DD, DD);
    gemm_bias_kernel<true><<<dim3(ED / 64, NN / 64), 256, 0, stream>>>(
        hb, DD + ED, W1, ED, b1, tb, ED, NN, ED, DD + ED);
    gemm_bias_kernel<false><<<dim3(ED / 64, NN / 64), 256, 0, stream>>>(
        tb, ED, W2, ED, b2, out, ED, NN, ED, ED);
}

// Round 5
// 119.728 us; speedup vs baseline: 7.1451x; 1.6320x over previous
//
#include <hip/hip_runtime.h>
#include <hip/hip_bf16.h>
#include <math.h>

#define NN   4096
#define KNB  10
#define ED   128
#define EFD  64
#define TD   64
#define DD   192     // E + T
#define KEYD 256     // E + EF + T
#define KDD  2560    // KEYD * KNB
#define HD   96      // DD / H
#define NH   2
#define NSPLIT 4     // K-splits for kv gemm and key-splits for attention

typedef __attribute__((ext_vector_type(8))) short bf16x8;
typedef __attribute__((ext_vector_type(4))) float f32x4;
typedef __attribute__((ext_vector_type(2))) unsigned int u32x2;

__device__ inline short f2bf(float f) {
    union { float f; unsigned int u; } c; c.f = f;
    unsigned int r = (c.u + 0x7FFFu + ((c.u >> 16) & 1u)) >> 16;
    return (short)r;
}

__device__ inline void gload_lds16(const void* g, void* lds) {
    __builtin_amdgcn_global_load_lds(
        (const __attribute__((address_space(1))) void*)g,
        (__attribute__((address_space(3))) void*)lds, 16, 0, 0);
}

// ---------------- transpose weights to bf16 [N][K] ----------------
// z=0: Wk[2560][192]->WkT[192][2560]; z=1: Wv->WvT; z=2: Wq[128][192]->WqT[192][128]
__global__ __launch_bounds__(256) void prep_wT(
    const float* __restrict__ Wk, const float* __restrict__ Wv,
    const float* __restrict__ Wq,
    short* __restrict__ WkT, short* __restrict__ WvT, short* __restrict__ WqT)
{
    int z = blockIdx.z;
    if (z == 2 && blockIdx.x >= 2) return;
    const float* W = (z == 0) ? Wk : (z == 1) ? Wv : Wq;
    short* WT = (z == 0) ? WkT : (z == 1) ? WvT : WqT;
    int ldk = (z == 2) ? ED : KDD;
    int k0 = blockIdx.x * 64, n0 = blockIdx.y * 64;
    __shared__ float ts[64][65];
    int t = threadIdx.x;
    // load 64k x 64n tile (coalesced along n)
    #pragma unroll
    for (int j = 0; j < 4; ++j) {
        int k = (t >> 4) + j * 16, n4 = (t & 15) * 4;
        float4 v = *(const float4*)&W[(size_t)(k0 + k) * DD + n0 + n4];
        ts[k][n4] = v.x; ts[k][n4 + 1] = v.y; ts[k][n4 + 2] = v.z; ts[k][n4 + 3] = v.w;
    }
    __syncthreads();
    // store transposed bf16 (coalesced along k)
    int n = t >> 2, kc = (t & 3) * 16;
    short tmp[16];
    #pragma unroll
    for (int j = 0; j < 16; ++j) tmp[j] = f2bf(ts[kc + j][n]);
    *(bf16x8*)&WT[(size_t)(n0 + n) * ldk + k0 + kc] = *(bf16x8*)&tmp[0];
    *(bf16x8*)&WT[(size_t)(n0 + n) * ldk + k0 + kc + 8] = *(bf16x8*)&tmp[8];
}

// ---------------- build agg [N, 2560] in bf16 ----------------
__global__ __launch_bounds__(256) void build_agg_bf16(
    const float* __restrict__ features, const float* __restrict__ edge_feats,
    const float* __restrict__ time_feats, const int* __restrict__ neighbors,
    short* __restrict__ agg)
{
    int n = blockIdx.x;
    int col = threadIdx.x; // 0..255 == KEYD
    #pragma unroll
    for (int k = 0; k < KNB; ++k) {
        int m = neighbors[n * KNB + k];
        float v;
        if (col < ED)            v = features[m * ED + col];
        else if (col < ED + EFD) v = edge_feats[(n * KNB + k) * EFD + (col - ED)];
        else                     v = time_feats[(n * KNB + k) * TD + (col - ED - EFD)];
        agg[(size_t)n * KDD + k * KEYD + col] = f2bf(v);
    }
}

// ---------------- gather x into h[:, 0:128] (ld=320) + xb bf16 ----------------
__global__ __launch_bounds__(256) void gather_x_kernel(
    const float* __restrict__ features, const int* __restrict__ node_idx,
    float* __restrict__ h, short* __restrict__ xb)
{
    int i = blockIdx.x * 256 + threadIdx.x; // over N*ED
    int n = i / ED, c = i % ED;
    float v = features[(size_t)node_idx[n] * ED + c];
    h[n * (DD + ED) + c] = v;
    xb[i] = f2bf(v);
}

// ---------------- generic fp32 GEMM: C = [relu](A @ B + bias) ----------------
template<bool RELU>
__global__ __launch_bounds__(256) void gemm_bias_kernel(
    const float* __restrict__ A, int lda,
    const float* __restrict__ B, int ldb,
    const float* __restrict__ bias,
    float* __restrict__ C, int ldc,
    int M, int Nc, int Kc)
{
    const int BK = 16, PAD = 4;
    __shared__ float As[BK][64 + PAD];
    __shared__ float Bs[BK][64 + PAD];
    int tid = threadIdx.x;
    int tx = tid % 16, ty = tid / 16;
    int m0 = blockIdx.y * 64;
    int n0 = blockIdx.x * 64;
    int a_m = tid / 4;
    int a_k = (tid % 4) * 4;
    int b_k = tid / 16;
    int b_n = (tid % 16) * 4;

    float acc[4][4] = {};
    for (int k0 = 0; k0 < Kc; k0 += BK) {
        float4 av = *(const float4*)&A[(size_t)(m0 + a_m) * lda + k0 + a_k];
        float4 bv = *(const float4*)&B[(size_t)(k0 + b_k) * ldb + n0 + b_n];
        As[a_k + 0][a_m] = av.x;
        As[a_k + 1][a_m] = av.y;
        As[a_k + 2][a_m] = av.z;
        As[a_k + 3][a_m] = av.w;
        *(float4*)&Bs[b_k][b_n] = bv;
        __syncthreads();
        #pragma unroll
        for (int k = 0; k < BK; ++k) {
            float4 a4 = *(const float4*)&As[k][ty * 4];
            float4 b4 = *(const float4*)&Bs[k][tx * 4];
            float aa[4] = {a4.x, a4.y, a4.z, a4.w};
            float bb[4] = {b4.x, b4.y, b4.z, b4.w};
            #pragma unroll
            for (int r = 0; r < 4; ++r)
                #pragma unroll
                for (int c = 0; c < 4; ++c)
                    acc[r][c] += aa[r] * bb[c];
        }
        __syncthreads();
    }
    #pragma unroll
    for (int r = 0; r < 4; ++r) {
        int row = m0 + ty * 4 + r;
        #pragma unroll
        for (int c = 0; c < 4; ++c) {
            int col = n0 + tx * 4 + c;
            float v = acc[r][c] + bias[col];
            if (RELU) v = fmaxf(v, 0.0f);
            C[(size_t)row * ldc + col] = v;
        }
    }
}

// ---------------- Q projection: qb = (x @ Wq[0:128] + bq) * scale, bf16 ----------------
__global__ __launch_bounds__(256) void gemm_q_mfma(
    const short* __restrict__ xb, const short* __restrict__ WqT,
    const float* __restrict__ bq, short* __restrict__ qb)
{
    __shared__ short As[64 * 64];
    __shared__ short Bs[64 * 64];
    int tid = threadIdx.x, wid = tid >> 6, lane = tid & 63;
    int lx = lane & 15, lg = lane >> 4;
    int m0 = blockIdx.y * 64, n0 = blockIdx.x * 64;
    int wm0 = (wid >> 1) * 32, wn0 = (wid & 1) * 32;
    f32x4 acc[2][2] = {};

    for (int k0 = 0; k0 < ED; k0 += 64) {
        #pragma unroll
        for (int it = 0; it < 2; ++it) {
            int idx = (wid * 2 + it) * 64 + lane;
            int m = idx >> 3, c = (idx & 7) ^ (m & 7);
            gload_lds16(xb + (size_t)(m0 + m) * ED + k0 + c * 8, &As[(wid * 2 + it) * 512]);
        }
        #pragma unroll
        for (int it = 0; it < 2; ++it) {
            int idx = (wid * 2 + it) * 64 + lane;
            int n = idx >> 3, c = (idx & 7) ^ (n & 7);
            gload_lds16(WqT + (size_t)(n0 + n) * ED + k0 + c * 8, &Bs[(wid * 2 + it) * 512]);
        }
        __syncthreads();
        #pragma unroll
        for (int ks = 0; ks < 2; ++ks) {
            bf16x8 af[2], bfr[2];
            #pragma unroll
            for (int mf = 0; mf < 2; ++mf) {
                int m = wm0 + mf * 16 + lx;
                af[mf] = *(const bf16x8*)&As[m * 64 + (((ks * 4 + lg) ^ (m & 7)) << 3)];
            }
            #pragma unroll
            for (int nf = 0; nf < 2; ++nf) {
                int n = wn0 + nf * 16 + lx;
                bfr[nf] = *(const bf16x8*)&Bs[n * 64 + (((ks * 4 + lg) ^ (n & 7)) << 3)];
            }
            #pragma unroll
            for (int mf = 0; mf < 2; ++mf)
                #pragma unroll
                for (int nf = 0; nf < 2; ++nf)
                    acc[mf][nf] = __builtin_amdgcn_mfma_f32_16x16x32_bf16(
                        af[mf], bfr[nf], acc[mf][nf], 0, 0, 0);
        }
        __syncthreads();
    }
    const float scale = 0.10206207261596577f; // 1/sqrt(96), folded into q
    #pragma unroll
    for (int nf = 0; nf < 2; ++nf) {
        int ncol = n0 + wn0 + nf * 16 + lx;
        float bb = bq[ncol];
        #pragma unroll
        for (int mf = 0; mf < 2; ++mf) {
            int mrow = m0 + wm0 + mf * 16 + 4 * lg;
            #pragma unroll
            for (int r = 0; r < 4; ++r)
                qb[(size_t)(mrow + r) * DD + ncol] = f2bf((acc[mf][nf][r] + bb) * scale);
        }
    }
}

// ---------------- K/V projection, K-split x4, double-buffered ----------------
// psumK [4][4096][192] fp32 ; psumV [4][192][4096] fp32 (V transposed)
__global__ __launch_bounds__(256) void kv_gemm_mfma(
    const short* __restrict__ agg,
    const short* __restrict__ WkT, const short* __restrict__ WvT,
    float* __restrict__ psumK, float* __restrict__ psumV)
{
    __shared__ short As[2][128 * 64];
    __shared__ short Bs[2][64 * 64];
    int tid = threadIdx.x, wid = tid >> 6, lane = tid & 63;
    int lx = lane & 15, lg = lane >> 4;
    // XCD-grouped decode: the 6 nb-blocks sharing an A-panel get ids = base + nb*8
    // (same id mod 8 -> same XCD under round-robin dispatch)
    int id = blockIdx.x;                // 0..767
    int xcd = id & 7, slot = id >> 3;   // slot 0..95
    int g = xcd * 16 + slot / 6;        // group 0..127  (mb, s)
    int nb = slot % 6;
    int mb = g >> 2, s = g & 3;
    bool isV = nb >= 3;
    const short* WT = isV ? WvT : WkT;
    int n0 = (nb - (isV ? 3 : 0)) * 64;
    int m0 = mb * 128;
    int wm0 = (wid >> 1) * 64, wn0 = (wid & 1) * 32;

    f32x4 acc[4][2] = {};

    auto stage = [&](int k0, int b) {
        #pragma unroll
        for (int it = 0; it < 4; ++it) {
            int idx = (wid * 4 + it) * 64 + lane;
            int m = idx >> 3, c = (idx & 7) ^ (m & 7);
            gload_lds16(agg + (size_t)(m0 + m) * KDD + k0 + c * 8,
                        &As[b][(wid * 4 + it) * 512]);
        }
        #pragma unroll
        for (int it = 0; it < 2; ++it) {
            int idx = (wid * 2 + it) * 64 + lane;
            int n = idx >> 3, c = (idx & 7) ^ (n & 7);
            gload_lds16(WT + (size_t)(n0 + n) * KDD + k0 + c * 8,
                        &Bs[b][(wid * 2 + it) * 512]);
        }
    };

    int kbase = s * (KDD / NSPLIT);     // 640 per split, 10 steps of 64
    stage(kbase, 0);
    for (int i = 0; i < 10; ++i) {
        int b = i & 1;
        __syncthreads();                 // drains staged loads for buf b
        if (i < 9) stage(kbase + (i + 1) * 64, b ^ 1);
        #pragma unroll
        for (int ks = 0; ks < 2; ++ks) {
            bf16x8 af[4], bfr[2];
            #pragma unroll
            for (int mf = 0; mf < 4; ++mf) {
                int m = wm0 + mf * 16 + lx;
                af[mf] = *(const bf16x8*)&As[b][m * 64 + (((ks * 4 + lg) ^ (m & 7)) << 3)];
            }
            #pragma unroll
            for (int nf = 0; nf < 2; ++nf) {
                int n = wn0 + nf * 16 + lx;
                bfr[nf] = *(const bf16x8*)&Bs[b][n * 64 + (((ks * 4 + lg) ^ (n & 7)) << 3)];
            }
            #pragma unroll
            for (int mf = 0; mf < 4; ++mf)
                #pragma unroll
                for (int nf = 0; nf < 2; ++nf)
                    acc[mf][nf] = __builtin_amdgcn_mfma_f32_16x16x32_bf16(
                        af[mf], bfr[nf], acc[mf][nf], 0, 0, 0);
        }
    }
    #pragma unroll
    for (int nf = 0; nf < 2; ++nf) {
        int ncol = n0 + wn0 + nf * 16 + lx;
        #pragma unroll
        for (int mf = 0; mf < 4; ++mf) {
            int mrow = m0 + wm0 + mf * 16 + 4 * lg;
            if (!isV) {
                #pragma unroll
                for (int r = 0; r < 4; ++r)
                    psumK[((size_t)s * NN + mrow + r) * DD + ncol] = acc[mf][nf][r];
            } else {
                float4 v4;
                v4.x = acc[mf][nf][0]; v4.y = acc[mf][nf][1];
                v4.z = acc[mf][nf][2]; v4.w = acc[mf][nf][3];
                *(float4*)&psumV[((size_t)(s * DD + ncol)) * NN + mrow] = v4;
            }
        }
    }
}

// ---------------- reduce K-splits, add bias, cast bf16 ----------------
__global__ __launch_bounds__(256) void kv_combine(
    const float* __restrict__ psumK, const float* __restrict__ psumV,
    const float* __restrict__ bk, const float* __restrict__ bv,
    short* __restrict__ kk, short* __restrict__ vvT)
{
    const int HALF = NN * DD / 4;       // float4 units per half
    int i = blockIdx.x * 256 + threadIdx.x;
    if (i < HALF) {
        int base = i * 4, n = base % DD;
        float4 sum = *(const float4*)&psumK[base];
        #pragma unroll
        for (int s = 1; s < NSPLIT; ++s) {
            float4 v = *(const float4*)&psumK[(size_t)s * NN * DD + base];
            sum.x += v.x; sum.y += v.y; sum.z += v.z; sum.w += v.w;
        }
        float4 bb = *(const float4*)&bk[n];
        short4 o;
        o.x = f2bf(sum.x + bb.x); o.y = f2bf(sum.y + bb.y);
        o.z = f2bf(sum.z + bb.z); o.w = f2bf(sum.w + bb.w);
        *(short4*)&kk[base] = o;
    } else {
        int j = i - HALF;
        int base = j * 4, n = base / NN;
        float4 sum = *(const float4*)&psumV[base];
        #pragma unroll
        for (int s = 1; s < NSPLIT; ++s) {
            float4 v = *(const float4*)&psumV[(size_t)s * DD * NN + base];
            sum.x += v.x; sum.y += v.y; sum.z += v.z; sum.w += v.w;
        }
        float bb = bv[n];
        short4 o;
        o.x = f2bf(sum.x + bb); o.y = f2bf(sum.y + bb);
        o.z = f2bf(sum.z + bb); o.w = f2bf(sum.w + bb);
        *(short4*)&vvT[base] = o;
    }
}

// ---------------- flash attention, bf16 MFMA, no-max softmax ----------------
// grid (N/64, heads, NSPLIT); 4 waves, wave = 16 q-rows; S^T via swapped MFMA.
__global__ __launch_bounds__(256) void attn_mfma(
    const short* __restrict__ qb,      // [4096][192] bf16, pre-scaled
    const short* __restrict__ kk,      // [4096][192] bf16
    const short* __restrict__ vvT,     // [192][4096] bf16
    float* __restrict__ opart,         // [4][4096][192] unnormalized
    float* __restrict__ ml)            // [4][2][4096] l-sums
{
    __shared__ short Ks[2][64 * 96];   // [key][d]
    __shared__ short Vs[2][96 * 64];   // [d][key], chunk^=(d&7) swizzled
    __shared__ short Ps[4][16 * 72];   // per-wave P [q][key], padded rows
    int tid = threadIdx.x, wid = tid >> 6, lane = tid & 63;
    int lx = lane & 15, lg = lane >> 4;
    int h = blockIdx.y, split = blockIdx.z;
    int hoff = h * HD;
    int qb0 = blockIdx.x * 64 + wid * 16;

    bf16x8 qf[3];
    #pragma unroll
    for (int ks = 0; ks < 3; ++ks)
        qf[ks] = *(const bf16x8*)&qb[(size_t)(qb0 + lx) * DD + hoff + ks * 32 + lg * 8];

    auto stage = [&](int kb, int b) {
        #pragma unroll
        for (int jj = 0; jj < 6; ++jj) {
            int j = wid * 6 + jj;
            if (j < 12) {                       // K tile: 64 rows x 12 chunks
                int idx = j * 64 + lane;
                int row = idx / 12, c = idx % 12;
                gload_lds16(kk + (size_t)(kb + row) * DD + hoff + c * 8,
                            &Ks[b][j * 512]);
            } else {                            // V tile: 96 rows x 8 chunks
                int idx = (j - 12) * 64 + lane;
                int d = idx >> 3, c = (idx & 7) ^ (d & 7);
                gload_lds16(vvT + (size_t)(hoff + d) * NN + kb + c * 8,
                            &Vs[b][(j - 12) * 512]);
            }
        }
    };

    float lsum = 0.0f;
    f32x4 accO[6] = {};
    short* myP = &Ps[wid][0];
    int kbase = split * (NN / NSPLIT);  // 1024 keys, 16 tiles of 64

    stage(kbase, 0);

    for (int t = 0; t < 16; ++t) {
        int b = t & 1;
        __syncthreads();  // staged loads for buf b drained; prev readers of b^1 done
        // ---- S^T = K @ Q^T : lane holds S^T[key=16nf+4lg+r][q=lx] ----
        f32x4 sf[4];
        #pragma unroll
        for (int nf = 0; nf < 4; ++nf) sf[nf] = (f32x4){0.f, 0.f, 0.f, 0.f};
        #pragma unroll
        for (int ks = 0; ks < 3; ++ks) {
            #pragma unroll
            for (int nf = 0; nf < 4; ++nf) {
                bf16x8 kf = *(const bf16x8*)&Ks[b][(nf * 16 + lx) * 96 + ks * 32 + lg * 8];
                sf[nf] = __builtin_amdgcn_mfma_f32_16x16x32_bf16(kf, qf[ks], sf[nf], 0, 0, 0);
            }
        }
        // ---- prefetch next tile into buf b^1 (no readers until next barrier) ----
        if (t < 15) stage(kbase + (t + 1) * 64, b ^ 1);
        // ---- softmax, no max subtraction (scores pre-scaled, |s| small) ----
        #pragma unroll
        for (int nf = 0; nf < 4; ++nf) {
            float p0 = __expf(sf[nf][0]);
            float p1 = __expf(sf[nf][1]);
            float p2 = __expf(sf[nf][2]);
            float p3 = __expf(sf[nf][3]);
            lsum += (p0 + p1) + (p2 + p3);
            unsigned int u0, u1;
            asm("v_cvt_pk_bf16_f32 %0, %1, %2" : "=v"(u0) : "v"(p0), "v"(p1));
            asm("v_cvt_pk_bf16_f32 %0, %1, %2" : "=v"(u1) : "v"(p2), "v"(p3));
            *(u32x2*)&myP[lx * 72 + nf * 16 + 4 * lg] = (u32x2){u0, u1};
        }
        // P rows written/read by same wave (DS ops in-order) -> no barrier
        #pragma unroll
        for (int kf2 = 0; kf2 < 2; ++kf2) {
            bf16x8 pf = *(const bf16x8*)&myP[lx * 72 + kf2 * 32 + lg * 8];
            #pragma unroll
            for (int nf2 = 0; nf2 < 6; ++nf2) {
                int d = nf2 * 16 + lx;
                bf16x8 vf = *(const bf16x8*)&Vs[b][d * 64 + (((kf2 * 4 + lg) ^ (d & 7)) << 3)];
                accO[nf2] = __builtin_amdgcn_mfma_f32_16x16x32_bf16(pf, vf, accO[nf2], 0, 0, 0);
            }
        }
    }

    float* op = opart + ((size_t)split * NN + qb0) * DD + hoff;
    #pragma unroll
    for (int nf2 = 0; nf2 < 6; ++nf2)
        #pragma unroll
        for (int r = 0; r < 4; ++r)
            op[(size_t)(4 * lg + r) * DD + nf2 * 16 + lx] = accO[nf2][r];
    lsum += __shfl_xor(lsum, 16);
    lsum += __shfl_xor(lsum, 32);
    if (lane < 16)
        ml[((size_t)(split * NH + h)) * NN + qb0 + lx] = lsum;
}

// ---------------- merge the key-splits ----------------
__global__ __launch_bounds__(256) void attn_combine(
    const float* __restrict__ opart, const float* __restrict__ ml,
    float* __restrict__ ob)
{
    int i = blockIdx.x * 256 + threadIdx.x;  // over NN*DD/4
    int base = i * 4;
    int row = base / DD, col = base % DD, h = col / HD;
    float4 o = *(const float4*)&opart[base];
    float l = ml[(size_t)(0 * NH + h) * NN + row];
    #pragma unroll
    for (int s = 1; s < NSPLIT; ++s) {
        float4 v = *(const float4*)&opart[(size_t)s * NN * DD + base];
        o.x += v.x; o.y += v.y; o.z += v.z; o.w += v.w;
        l += ml[(size_t)(s * NH + h) * NN + row];
    }
    float inv = 1.0f / l;
    o.x *= inv; o.y *= inv; o.z *= inv; o.w *= inv;
    *(float4*)&ob[base] = o;
}

extern "C" void kernel_launch(void* const* d_in, const int* in_sizes, int n_in,
                              void* d_out, int out_size, void* d_ws, size_t ws_size,
                              hipStream_t stream) {
    const float* features   = (const float*)d_in[0];
    const float* edge_feats = (const float*)d_in[1];
    const float* time_feats = (const float*)d_in[2];
    const int*   neighbors  = (const int*)d_in[3];
    const int*   node_idx   = (const int*)d_in[4];
    const float* Wq = (const float*)d_in[5];
    const float* bq = (const float*)d_in[6];
    const float* Wk = (const float*)d_in[7];
    const float* bk = (const float*)d_in[8];
    const float* Wv = (const float*)d_in[9];
    const float* bv = (const float*)d_in[10];
    const float* Wo = (const float*)d_in[11];
    const float* bo = (const float*)d_in[12];
    const float* W1 = (const float*)d_in[13];
    const float* b1 = (const float*)d_in[14];
    const float* W2 = (const float*)d_in[15];
    const float* b2 = (const float*)d_in[16];
    float* out = (float*)d_out;

    char* w = (char*)d_ws;
    short* agg  = (short*)w;  w += (size_t)NN * KDD * 2;        // 20.97 MB
    short* qb   = (short*)w;  w += (size_t)NN * DD * 2;
    short* kkb  = (short*)w;  w += (size_t)NN * DD * 2;
    short* vvT  = (short*)w;  w += (size_t)DD * NN * 2;
    short* WkT  = (short*)w;  w += (size_t)DD * KDD * 2;
    short* WvT  = (short*)w;  w += (size_t)DD * KDD * 2;
    short* WqT  = (short*)w;  w += (size_t)DD * ED * 2;
    short* xb   = (short*)w;  w += (size_t)NN * ED * 2;
    float* hb   = (float*)w;  w += (size_t)NN * (DD + ED) * 4;
    float* tb   = (float*)w;  w += (size_t)NN * ED * 4;
    // scratch region: (psumK|psumV) then reused as (opart|ml|ob)
    float* psumK = (float*)w;
    float* psumV = psumK + (size_t)NSPLIT * NN * DD;
    float* opart = (float*)w;
    float* ml    = opart + (size_t)NSPLIT * NN * DD;
    float* ob    = ml + (size_t)NSPLIT * NH * NN;

    prep_wT<<<dim3(KDD / 64, DD / 64, 3), 256, 0, stream>>>(Wk, Wv, Wq, WkT, WvT, WqT);
    build_agg_bf16<<<NN, 256, 0, stream>>>(features, edge_feats, time_feats,
                                           neighbors, agg);
    gather_x_kernel<<<(NN * ED) / 256, 256, 0, stream>>>(features, node_idx, hb, xb);
    gemm_q_mfma<<<dim3(DD / 64, NN / 64), 256, 0, stream>>>(xb, WqT, bq, qb);
    kv_gemm_mfma<<<6 * (NN / 128) * NSPLIT, 256, 0, stream>>>(agg, WkT, WvT, psumK, psumV);
    kv_combine<<<2 * NN * DD / 4 / 256, 256, 0, stream>>>(psumK, psumV, bk, bv, kkb, vvT);
    attn_mfma<<<dim3(NN / 64, NH, NSPLIT), 256, 0, stream>>>(qb, kkb, vvT, opart, ml);
    attn_combine<<<NN * DD / 4 / 256, 256, 0, stream>>>(opart, ml, ob);
    gemm_bias_kernel<false><<<dim3(DD / 64, NN / 64), 256, 0, stream>>>(
        ob, DD, Wo, DD, bo, hb + ED, DD + ED, NN, DD, DD);
    gemm_bias_kernel<true><<<dim3(ED / 64, NN / 64), 256, 0, stream>>>(
        hb, DD + ED, W1, ED, b1, tb, ED, NN, ED, DD + ED);
    gemm_bias_kernel<false><<<dim3(ED / 64, NN / 64), 256, 0, stream>>>(
        tb, ED, W2, ED, b2, out, ED, NN, ED, ED);
}

// Round 7
// 90.666 us; speedup vs baseline: 9.4354x; 1.3205x over previous
//
#include <hip/hip_runtime.h>
#include <hip/hip_bf16.h>
#include <math.h>

#define NN   4096
#define KNB  10
#define ED   128
#define EFD  64
#define TD   64
#define DD   192     // E + T
#define KEYD 256     // E + EF + T
#define KDD  2560    // KEYD * KNB
#define HD   96      // DD / H
#define NH   2
#define NSPLIT 4     // K-splits for kv gemm and key-splits for attention

typedef __attribute__((ext_vector_type(8))) short bf16x8;
typedef __attribute__((ext_vector_type(4))) float f32x4;
typedef __attribute__((ext_vector_type(2))) unsigned int u32x2;

__device__ inline short f2bf(float f) {
    union { float f; unsigned int u; } c; c.f = f;
    unsigned int r = (c.u + 0x7FFFu + ((c.u >> 16) & 1u)) >> 16;
    return (short)r;
}

__device__ inline void gload_lds16(const void* g, void* lds) {
    __builtin_amdgcn_global_load_lds(
        (const __attribute__((address_space(1))) void*)g,
        (__attribute__((address_space(3))) void*)lds, 16, 0, 0);
}

// ---------------- transpose weights to bf16 [N][K] ----------------
// z=0: Wk[2560][192]->WkT[192][2560]; z=1: Wv->WvT; z=2: Wq[128][192]->WqT[192][128]
__global__ __launch_bounds__(256) void prep_wT(
    const float* __restrict__ Wk, const float* __restrict__ Wv,
    const float* __restrict__ Wq,
    short* __restrict__ WkT, short* __restrict__ WvT, short* __restrict__ WqT)
{
    int z = blockIdx.z;
    if (z == 2 && blockIdx.x >= 2) return;
    const float* W = (z == 0) ? Wk : (z == 1) ? Wv : Wq;
    short* WT = (z == 0) ? WkT : (z == 1) ? WvT : WqT;
    int ldk = (z == 2) ? ED : KDD;
    int k0 = blockIdx.x * 64, n0 = blockIdx.y * 64;
    __shared__ float ts[64][65];
    int t = threadIdx.x;
    #pragma unroll
    for (int j = 0; j < 4; ++j) {
        int k = (t >> 4) + j * 16, n4 = (t & 15) * 4;
        float4 v = *(const float4*)&W[(size_t)(k0 + k) * DD + n0 + n4];
        ts[k][n4] = v.x; ts[k][n4 + 1] = v.y; ts[k][n4 + 2] = v.z; ts[k][n4 + 3] = v.w;
    }
    __syncthreads();
    int n = t >> 2, kc = (t & 3) * 16;
    short tmp[16];
    #pragma unroll
    for (int j = 0; j < 16; ++j) tmp[j] = f2bf(ts[kc + j][n]);
    *(bf16x8*)&WT[(size_t)(n0 + n) * ldk + k0 + kc] = *(bf16x8*)&tmp[0];
    *(bf16x8*)&WT[(size_t)(n0 + n) * ldk + k0 + kc + 8] = *(bf16x8*)&tmp[8];
}

// ---------------- MLP weight fold:  Wfold = Wo @ W1b,  bfold = bo @ W1b + b1 ----------------
// WcatT [128 n][320 k] bf16: k<128 -> W1a[k][n]; k>=128 -> Wfold[k-128][n].
// W2T [128 n][128 k] bf16.
__global__ __launch_bounds__(320) void prep_mlp(
    const float* __restrict__ Wo, const float* __restrict__ bo,
    const float* __restrict__ W1, const float* __restrict__ b1,
    const float* __restrict__ W2,
    short* __restrict__ WcatT, short* __restrict__ W2T, float* __restrict__ bfold)
{
    int n = blockIdx.x;       // 0..127
    int k = threadIdx.x;      // 0..319
    if (k < 128) {
        WcatT[n * 320 + k] = f2bf(W1[(size_t)k * ED + n]);
        W2T[n * 128 + k]   = f2bf(W2[(size_t)k * ED + n]);
        if (k == 0) {
            float s = 0.f;
            for (int j = 0; j < DD; ++j) s += bo[j] * W1[(size_t)(ED + j) * ED + n];
            bfold[n] = s + b1[n];
        }
    } else {
        int d = k - 128;      // 0..191
        float s = 0.f;
        for (int j = 0; j < DD; ++j) s += Wo[(size_t)d * DD + j] * W1[(size_t)(ED + j) * ED + n];
        WcatT[n * 320 + k] = f2bf(s);
    }
}

// ---------------- build agg [N, 2560] bf16 + xb [N,128] bf16 ----------------
__global__ __launch_bounds__(256) void build_agg_x(
    const float* __restrict__ features, const float* __restrict__ edge_feats,
    const float* __restrict__ time_feats, const int* __restrict__ neighbors,
    const int* __restrict__ node_idx,
    short* __restrict__ agg, short* __restrict__ xb)
{
    int n = blockIdx.x;
    int col = threadIdx.x; // 0..255 == KEYD
    #pragma unroll
    for (int k = 0; k < KNB; ++k) {
        int m = neighbors[n * KNB + k];
        float v;
        if (col < ED)            v = features[m * ED + col];
        else if (col < ED + EFD) v = edge_feats[(n * KNB + k) * EFD + (col - ED)];
        else                     v = time_feats[(n * KNB + k) * TD + (col - ED - EFD)];
        agg[(size_t)n * KDD + k * KEYD + col] = f2bf(v);
    }
    if (col < ED)
        xb[n * ED + col] = f2bf(features[(size_t)node_idx[n] * ED + col]);
}

// ---------------- Q projection: qb = (x @ Wq[0:128] + bq) * scale, bf16 ----------------
__global__ __launch_bounds__(256) void gemm_q_mfma(
    const short* __restrict__ xb, const short* __restrict__ WqT,
    const float* __restrict__ bq, short* __restrict__ qb)
{
    __shared__ short As[64 * 64];
    __shared__ short Bs[64 * 64];
    int tid = threadIdx.x, wid = tid >> 6, lane = tid & 63;
    int lx = lane & 15, lg = lane >> 4;
    int m0 = blockIdx.y * 64, n0 = blockIdx.x * 64;
    int wm0 = (wid >> 1) * 32, wn0 = (wid & 1) * 32;
    f32x4 acc[2][2] = {};

    for (int k0 = 0; k0 < ED; k0 += 64) {
        #pragma unroll
        for (int it = 0; it < 2; ++it) {
            int idx = (wid * 2 + it) * 64 + lane;
            int m = idx >> 3, c = (idx & 7) ^ (m & 7);
            gload_lds16(xb + (size_t)(m0 + m) * ED + k0 + c * 8, &As[(wid * 2 + it) * 512]);
        }
        #pragma unroll
        for (int it = 0; it < 2; ++it) {
            int idx = (wid * 2 + it) * 64 + lane;
            int n = idx >> 3, c = (idx & 7) ^ (n & 7);
            gload_lds16(WqT + (size_t)(n0 + n) * ED + k0 + c * 8, &Bs[(wid * 2 + it) * 512]);
        }
        __syncthreads();
        #pragma unroll
        for (int ks = 0; ks < 2; ++ks) {
            bf16x8 af[2], bfr[2];
            #pragma unroll
            for (int mf = 0; mf < 2; ++mf) {
                int m = wm0 + mf * 16 + lx;
                af[mf] = *(const bf16x8*)&As[m * 64 + (((ks * 4 + lg) ^ (m & 7)) << 3)];
            }
            #pragma unroll
            for (int nf = 0; nf < 2; ++nf) {
                int n = wn0 + nf * 16 + lx;
                bfr[nf] = *(const bf16x8*)&Bs[n * 64 + (((ks * 4 + lg) ^ (n & 7)) << 3)];
            }
            #pragma unroll
            for (int mf = 0; mf < 2; ++mf)
                #pragma unroll
                for (int nf = 0; nf < 2; ++nf)
                    acc[mf][nf] = __builtin_amdgcn_mfma_f32_16x16x32_bf16(
                        af[mf], bfr[nf], acc[mf][nf], 0, 0, 0);
        }
        __syncthreads();
    }
    const float scale = 0.10206207261596577f; // 1/sqrt(96), folded into q
    #pragma unroll
    for (int nf = 0; nf < 2; ++nf) {
        int ncol = n0 + wn0 + nf * 16 + lx;
        float bb = bq[ncol];
        #pragma unroll
        for (int mf = 0; mf < 2; ++mf) {
            int mrow = m0 + wm0 + mf * 16 + 4 * lg;
            #pragma unroll
            for (int r = 0; r < 4; ++r)
                qb[(size_t)(mrow + r) * DD + ncol] = f2bf((acc[mf][nf][r] + bb) * scale);
        }
    }
}

// ---------------- K/V projection, K-split x4, double-buffered ----------------
__global__ __launch_bounds__(256) void kv_gemm_mfma(
    const short* __restrict__ agg,
    const short* __restrict__ WkT, const short* __restrict__ WvT,
    float* __restrict__ psumK, float* __restrict__ psumV)
{
    __shared__ short As[2][128 * 64];
    __shared__ short Bs[2][64 * 64];
    int tid = threadIdx.x, wid = tid >> 6, lane = tid & 63;
    int lx = lane & 15, lg = lane >> 4;
    int id = blockIdx.x;                // 0..767
    int xcd = id & 7, slot = id >> 3;
    int g = xcd * 16 + slot / 6;
    int nb = slot % 6;
    int mb = g >> 2, s = g & 3;
    bool isV = nb >= 3;
    const short* WT = isV ? WvT : WkT;
    int n0 = (nb - (isV ? 3 : 0)) * 64;
    int m0 = mb * 128;
    int wm0 = (wid >> 1) * 64, wn0 = (wid & 1) * 32;

    f32x4 acc[4][2] = {};

    auto stage = [&](int k0, int b) {
        #pragma unroll
        for (int it = 0; it < 4; ++it) {
            int idx = (wid * 4 + it) * 64 + lane;
            int m = idx >> 3, c = (idx & 7) ^ (m & 7);
            gload_lds16(agg + (size_t)(m0 + m) * KDD + k0 + c * 8,
                        &As[b][(wid * 4 + it) * 512]);
        }
        #pragma unroll
        for (int it = 0; it < 2; ++it) {
            int idx = (wid * 2 + it) * 64 + lane;
            int n = idx >> 3, c = (idx & 7) ^ (n & 7);
            gload_lds16(WT + (size_t)(n0 + n) * KDD + k0 + c * 8,
                        &Bs[b][(wid * 2 + it) * 512]);
        }
    };

    int kbase = s * (KDD / NSPLIT);
    stage(kbase, 0);
    for (int i = 0; i < 10; ++i) {
        int b = i & 1;
        __syncthreads();
        if (i < 9) stage(kbase + (i + 1) * 64, b ^ 1);
        #pragma unroll
        for (int ks = 0; ks < 2; ++ks) {
            bf16x8 af[4], bfr[2];
            #pragma unroll
            for (int mf = 0; mf < 4; ++mf) {
                int m = wm0 + mf * 16 + lx;
                af[mf] = *(const bf16x8*)&As[b][m * 64 + (((ks * 4 + lg) ^ (m & 7)) << 3)];
            }
            #pragma unroll
            for (int nf = 0; nf < 2; ++nf) {
                int n = wn0 + nf * 16 + lx;
                bfr[nf] = *(const bf16x8*)&Bs[b][n * 64 + (((ks * 4 + lg) ^ (n & 7)) << 3)];
            }
            #pragma unroll
            for (int mf = 0; mf < 4; ++mf)
                #pragma unroll
                for (int nf = 0; nf < 2; ++nf)
                    acc[mf][nf] = __builtin_amdgcn_mfma_f32_16x16x32_bf16(
                        af[mf], bfr[nf], acc[mf][nf], 0, 0, 0);
        }
    }
    #pragma unroll
    for (int nf = 0; nf < 2; ++nf) {
        int ncol = n0 + wn0 + nf * 16 + lx;
        #pragma unroll
        for (int mf = 0; mf < 4; ++mf) {
            int mrow = m0 + wm0 + mf * 16 + 4 * lg;
            if (!isV) {
                #pragma unroll
                for (int r = 0; r < 4; ++r)
                    psumK[((size_t)s * NN + mrow + r) * DD + ncol] = acc[mf][nf][r];
            } else {
                float4 v4;
                v4.x = acc[mf][nf][0]; v4.y = acc[mf][nf][1];
                v4.z = acc[mf][nf][2]; v4.w = acc[mf][nf][3];
                *(float4*)&psumV[((size_t)(s * DD + ncol)) * NN + mrow] = v4;
            }
        }
    }
}

// ---------------- reduce K-splits, add bias, cast bf16 ----------------
__global__ __launch_bounds__(256) void kv_combine(
    const float* __restrict__ psumK, const float* __restrict__ psumV,
    const float* __restrict__ bk, const float* __restrict__ bv,
    short* __restrict__ kk, short* __restrict__ vvT)
{
    const int HALF = NN * DD / 4;
    int i = blockIdx.x * 256 + threadIdx.x;
    if (i < HALF) {
        int base = i * 4, n = base % DD;
        float4 sum = *(const float4*)&psumK[base];
        #pragma unroll
        for (int s = 1; s < NSPLIT; ++s) {
            float4 v = *(const float4*)&psumK[(size_t)s * NN * DD + base];
            sum.x += v.x; sum.y += v.y; sum.z += v.z; sum.w += v.w;
        }
        float4 bb = *(const float4*)&bk[n];
        short4 o;
        o.x = f2bf(sum.x + bb.x); o.y = f2bf(sum.y + bb.y);
        o.z = f2bf(sum.z + bb.z); o.w = f2bf(sum.w + bb.w);
        *(short4*)&kk[base] = o;
    } else {
        int j = i - HALF;
        int base = j * 4, n = base / NN;
        float4 sum = *(const float4*)&psumV[base];
        #pragma unroll
        for (int s = 1; s < NSPLIT; ++s) {
            float4 v = *(const float4*)&psumV[(size_t)s * DD * NN + base];
            sum.x += v.x; sum.y += v.y; sum.z += v.z; sum.w += v.w;
        }
        float bb = bv[n];
        short4 o;
        o.x = f2bf(sum.x + bb); o.y = f2bf(sum.y + bb);
        o.z = f2bf(sum.z + bb); o.w = f2bf(sum.w + bb);
        *(short4*)&vvT[base] = o;
    }
}

// ---------------- flash attention, bf16 MFMA, no-max softmax ----------------
__global__ __launch_bounds__(256) void attn_mfma(
    const short* __restrict__ qb,      // [4096][192] bf16, pre-scaled
    const short* __restrict__ kk,      // [4096][192] bf16
    const short* __restrict__ vvT,     // [192][4096] bf16
    float* __restrict__ opart,         // [4][4096][192] unnormalized
    float* __restrict__ ml)            // [4][2][4096] l-sums
{
    __shared__ short Ks[2][64 * 96];
    __shared__ short Vs[2][96 * 64];
    __shared__ short Ps[4][16 * 72];
    int tid = threadIdx.x, wid = tid >> 6, lane = tid & 63;
    int lx = lane & 15, lg = lane >> 4;
    int h = blockIdx.y, split = blockIdx.z;
    int hoff = h * HD;
    int qb0 = blockIdx.x * 64 + wid * 16;

    bf16x8 qf[3];
    #pragma unroll
    for (int ks = 0; ks < 3; ++ks)
        qf[ks] = *(const bf16x8*)&qb[(size_t)(qb0 + lx) * DD + hoff + ks * 32 + lg * 8];

    auto stage = [&](int kb, int b) {
        #pragma unroll
        for (int jj = 0; jj < 6; ++jj) {
            int j = wid * 6 + jj;
            if (j < 12) {
                int idx = j * 64 + lane;
                int row = idx / 12, c = idx % 12;
                gload_lds16(kk + (size_t)(kb + row) * DD + hoff + c * 8,
                            &Ks[b][j * 512]);
            } else {
                int idx = (j - 12) * 64 + lane;
                int d = idx >> 3, c = (idx & 7) ^ (d & 7);
                gload_lds16(vvT + (size_t)(hoff + d) * NN + kb + c * 8,
                            &Vs[b][(j - 12) * 512]);
            }
        }
    };

    float lsum = 0.0f;
    f32x4 accO[6] = {};
    short* myP = &Ps[wid][0];
    int kbase = split * (NN / NSPLIT);

    stage(kbase, 0);

    for (int t = 0; t < 16; ++t) {
        int b = t & 1;
        __syncthreads();
        f32x4 sf[4];
        #pragma unroll
        for (int nf = 0; nf < 4; ++nf) sf[nf] = (f32x4){0.f, 0.f, 0.f, 0.f};
        #pragma unroll
        for (int ks = 0; ks < 3; ++ks) {
            #pragma unroll
            for (int nf = 0; nf < 4; ++nf) {
                bf16x8 kf = *(const bf16x8*)&Ks[b][(nf * 16 + lx) * 96 + ks * 32 + lg * 8];
                sf[nf] = __builtin_amdgcn_mfma_f32_16x16x32_bf16(kf, qf[ks], sf[nf], 0, 0, 0);
            }
        }
        if (t < 15) stage(kbase + (t + 1) * 64, b ^ 1);
        #pragma unroll
        for (int nf = 0; nf < 4; ++nf) {
            float p0 = __expf(sf[nf][0]);
            float p1 = __expf(sf[nf][1]);
            float p2 = __expf(sf[nf][2]);
            float p3 = __expf(sf[nf][3]);
            lsum += (p0 + p1) + (p2 + p3);
            unsigned int u0, u1;
            asm("v_cvt_pk_bf16_f32 %0, %1, %2" : "=v"(u0) : "v"(p0), "v"(p1));
            asm("v_cvt_pk_bf16_f32 %0, %1, %2" : "=v"(u1) : "v"(p2), "v"(p3));
            *(u32x2*)&myP[lx * 72 + nf * 16 + 4 * lg] = (u32x2){u0, u1};
        }
        #pragma unroll
        for (int kf2 = 0; kf2 < 2; ++kf2) {
            bf16x8 pf = *(const bf16x8*)&myP[lx * 72 + kf2 * 32 + lg * 8];
            #pragma unroll
            for (int nf2 = 0; nf2 < 6; ++nf2) {
                int d = nf2 * 16 + lx;
                bf16x8 vf = *(const bf16x8*)&Vs[b][d * 64 + (((kf2 * 4 + lg) ^ (d & 7)) << 3)];
                accO[nf2] = __builtin_amdgcn_mfma_f32_16x16x32_bf16(pf, vf, accO[nf2], 0, 0, 0);
            }
        }
    }

    float* op = opart + ((size_t)split * NN + qb0) * DD + hoff;
    #pragma unroll
    for (int nf2 = 0; nf2 < 6; ++nf2)
        #pragma unroll
        for (int r = 0; r < 4; ++r)
            op[(size_t)(4 * lg + r) * DD + nf2 * 16 + lx] = accO[nf2][r];
    lsum += __shfl_xor(lsum, 16);
    lsum += __shfl_xor(lsum, 32);
    if (lane < 16)
        ml[((size_t)(split * NH + h)) * NN + qb0 + lx] = lsum;
}

// ---------------- fused MLP: out = relu([x|ob] @ Wcat + bfold) @ W2 + b2 ----------------
// 32 rows/block, grid 128. Combines split-merge + normalize into A-staging.
__global__ __launch_bounds__(256) void mlp_fused(
    const short* __restrict__ xb,      // [4096][128] bf16
    const float* __restrict__ opart,   // [4][4096][192] fp32
    const float* __restrict__ ml,      // [4][2][4096] fp32
    const short* __restrict__ WcatT,   // [128][320] bf16
    const float* __restrict__ bfold,   // [128]
    const short* __restrict__ W2T,     // [128][128] bf16
    const float* __restrict__ b2,      // [128]
    float* __restrict__ out)           // [4096][128] fp32
{
    __shared__ short As[32 * 64];      // 4 KB
    __shared__ short Bs[128 * 64];     // 16 KB
    __shared__ short Ts[32 * 128];     // 8 KB
    __shared__ float linv[64];
    int tid = threadIdx.x, wid = tid >> 6, lane = tid & 63;
    int lx = lane & 15, lg = lane >> 4;
    int m0 = blockIdx.x * 32;
    int wm0 = (wid >> 1) * 16, wn0 = (wid & 1) * 64;

    if (tid < 64) {
        int rl = tid >> 1, hh = tid & 1;
        float l = 0.f;
        #pragma unroll
        for (int s = 0; s < NSPLIT; ++s) l += ml[(size_t)(s * NH + hh) * NN + m0 + rl];
        linv[tid] = 1.0f / l;
    }

    f32x4 acc[4] = {};
    for (int step = 0; step < 5; ++step) {
        int k0 = step * 64;
        if (step < 2) {
            int idx = wid * 64 + lane;
            int m = idx >> 3, c = (idx & 7) ^ (m & 7);
            gload_lds16(xb + (size_t)(m0 + m) * ED + k0 + c * 8, &As[wid * 512]);
        } else {
            int m = tid >> 3, j8 = tid & 7;
            int dg = (k0 - 128) + j8 * 8;  // global attn-dim base, 8 elems (head-uniform)
            float sum[8];
            float4 a0 = *(const float4*)&opart[((size_t)0 * NN + m0 + m) * DD + dg];
            float4 a1 = *(const float4*)&opart[((size_t)0 * NN + m0 + m) * DD + dg + 4];
            sum[0] = a0.x; sum[1] = a0.y; sum[2] = a0.z; sum[3] = a0.w;
            sum[4] = a1.x; sum[5] = a1.y; sum[6] = a1.z; sum[7] = a1.w;
            #pragma unroll
            for (int s = 1; s < NSPLIT; ++s) {
                float4 b0 = *(const float4*)&opart[((size_t)s * NN + m0 + m) * DD + dg];
                float4 b1v = *(const float4*)&opart[((size_t)s * NN + m0 + m) * DD + dg + 4];
                sum[0] += b0.x; sum[1] += b0.y; sum[2] += b0.z; sum[3] += b0.w;
                sum[4] += b1v.x; sum[5] += b1v.y; sum[6] += b1v.z; sum[7] += b1v.w;
            }
            float inv = linv[m * 2 + (dg >= HD ? 1 : 0)];
            short tmp[8];
            #pragma unroll
            for (int j = 0; j < 8; ++j) tmp[j] = f2bf(sum[j] * inv);
            *(bf16x8*)&As[m * 64 + ((j8 ^ (m & 7)) << 3)] = *(bf16x8*)&tmp[0];
        }
        #pragma unroll
        for (int it = 0; it < 4; ++it) {
            int idx = (wid * 4 + it) * 64 + lane;
            int n = idx >> 3, c = (idx & 7) ^ (n & 7);
            gload_lds16(WcatT + (size_t)n * 320 + k0 + c * 8, &Bs[(wid * 4 + it) * 512]);
        }
        __syncthreads();
        #pragma unroll
        for (int kss = 0; kss < 2; ++kss) {
            int m = wm0 + lx;
            bf16x8 af = *(const bf16x8*)&As[m * 64 + (((kss * 4 + lg) ^ (m & 7)) << 3)];
            #pragma unroll
            for (int nf = 0; nf < 4; ++nf) {
                int n = wn0 + nf * 16 + lx;
                bf16x8 bfr = *(const bf16x8*)&Bs[n * 64 + (((kss * 4 + lg) ^ (n & 7)) << 3)];
                acc[nf] = __builtin_amdgcn_mfma_f32_16x16x32_bf16(af, bfr, acc[nf], 0, 0, 0);
            }
        }
        __syncthreads();
    }
    // t = relu(acc + bfold) -> Ts swizzled [m][16 chunks]
    #pragma unroll
    for (int nf = 0; nf < 4; ++nf) {
        int kcol = wn0 + nf * 16 + lx;
        float bb = bfold[kcol];
        #pragma unroll
        for (int r = 0; r < 4; ++r) {
            int m = wm0 + 4 * lg + r;
            float v = fmaxf(acc[nf][r] + bb, 0.f);
            Ts[m * 128 + ((((kcol >> 3) ^ (m & 7)) << 3) | (kcol & 7))] = f2bf(v);
        }
    }
    __syncthreads();
    // out = t @ W2 + b2
    f32x4 acc2[4] = {};
    #pragma unroll
    for (int step = 0; step < 2; ++step) {
        int k0 = step * 64;
        #pragma unroll
        for (int it = 0; it < 4; ++it) {
            int idx = (wid * 4 + it) * 64 + lane;
            int n = idx >> 3, c = (idx & 7) ^ (n & 7);
            gload_lds16(W2T + (size_t)n * 128 + k0 + c * 8, &Bs[(wid * 4 + it) * 512]);
        }
        __syncthreads();
        #pragma unroll
        for (int kss = 0; kss < 2; ++kss) {
            int m = wm0 + lx;
            int chunk = step * 8 + kss * 4 + lg;
            bf16x8 af = *(const bf16x8*)&Ts[m * 128 + ((chunk ^ (m & 7)) << 3)];
            #pragma unroll
            for (int nf = 0; nf < 4; ++nf) {
                int n = wn0 + nf * 16 + lx;
                bf16x8 bfr = *(const bf16x8*)&Bs[n * 64 + (((kss * 4 + lg) ^ (n & 7)) << 3)];
                acc2[nf] = __builtin_amdgcn_mfma_f32_16x16x32_bf16(af, bfr, acc2[nf], 0, 0, 0);
            }
        }
        __syncthreads();
    }
    #pragma unroll
    for (int nf = 0; nf < 4; ++nf) {
        int ncol = wn0 + nf * 16 + lx;
        float bb = b2[ncol];
        #pragma unroll
        for (int r = 0; r < 4; ++r)
            out[(size_t)(m0 + wm0 + 4 * lg + r) * 128 + ncol] = acc2[nf][r] + bb;
    }
}

extern "C" void kernel_launch(void* const* d_in, const int* in_sizes, int n_in,
                              void* d_out, int out_size, void* d_ws, size_t ws_size,
                              hipStream_t stream) {
    const float* features   = (const float*)d_in[0];
    const float* edge_feats = (const float*)d_in[1];
    const float* time_feats = (const float*)d_in[2];
    const int*   neighbors  = (const int*)d_in[3];
    const int*   node_idx   = (const int*)d_in[4];
    const float* Wq = (const float*)d_in[5];
    const float* bq = (const float*)d_in[6];
    const float* Wk = (const float*)d_in[7];
    const float* bk = (const float*)d_in[8];
    const float* Wv = (const float*)d_in[9];
    const float* bv = (const float*)d_in[10];
    const float* Wo = (const float*)d_in[11];
    const float* bo = (const float*)d_in[12];
    const float* W1 = (const float*)d_in[13];
    const float* b1 = (const float*)d_in[14];
    const float* W2 = (const float*)d_in[15];
    const float* b2 = (const float*)d_in[16];
    float* out = (float*)d_out;

    char* w = (char*)d_ws;
    short* agg   = (short*)w;  w += (size_t)NN * KDD * 2;
    short* qb    = (short*)w;  w += (size_t)NN * DD * 2;
    short* kkb   = (short*)w;  w += (size_t)NN * DD * 2;
    short* vvT   = (short*)w;  w += (size_t)DD * NN * 2;
    short* WkT   = (short*)w;  w += (size_t)DD * KDD * 2;
    short* WvT   = (short*)w;  w += (size_t)DD * KDD * 2;
    short* WqT   = (short*)w;  w += (size_t)DD * ED * 2;
    short* xb    = (short*)w;  w += (size_t)NN * ED * 2;
    short* WcatT = (short*)w;  w += (size_t)ED * 320 * 2;
    short* W2T   = (short*)w;  w += (size_t)ED * ED * 2;
    float* bfold = (float*)w;  w += (size_t)ED * 4;
    // scratch region: (psumK|psumV) then reused as (opart|ml)
    float* psumK = (float*)w;
    float* psumV = psumK + (size_t)NSPLIT * NN * DD;
    float* opart = (float*)w;
    float* ml    = opart + (size_t)NSPLIT * NN * DD;

    prep_wT<<<dim3(KDD / 64, DD / 64, 3), 256, 0, stream>>>(Wk, Wv, Wq, WkT, WvT, WqT);
    prep_mlp<<<ED, 320, 0, stream>>>(Wo, bo, W1, b1, W2, WcatT, W2T, bfold);
    build_agg_x<<<NN, 256, 0, stream>>>(features, edge_feats, time_feats,
                                        neighbors, node_idx, agg, xb);
    gemm_q_mfma<<<dim3(DD / 64, NN / 64), 256, 0, stream>>>(xb, WqT, bq, qb);
    kv_gemm_mfma<<<6 * (NN / 128) * NSPLIT, 256, 0, stream>>>(agg, WkT, WvT, psumK, psumV);
    kv_combine<<<2 * NN * DD / 4 / 256, 256, 0, stream>>>(psumK, psumV, bk, bv, kkb, vvT);
    attn_mfma<<<dim3(NN / 64, NH, NSPLIT), 256, 0, stream>>>(qb, kkb, vvT, opart, ml);
    mlp_fused<<<NN / 32, 256, 0, stream>>>(xb, opart, ml, WcatT, bfold, W2T, b2, out);
}

// Round 10
// 85.296 us; speedup vs baseline: 10.0294x; 1.0630x over previous
//
#include <hip/hip_runtime.h>
#include <hip/hip_bf16.h>
#include <math.h>

#define NN   4096
#define KNB  10
#define ED   128
#define EFD  64
#define TD   64
#define DD   192     // E + T
#define KEYD 256     // E + EF + T
#define KDD  2560    // KEYD * KNB
#define HD   96      // DD / H
#define NH   2
#define NSPLIT 4     // K-splits for kv gemm and key-splits for attention

typedef __attribute__((ext_vector_type(8))) short bf16x8;
typedef __attribute__((ext_vector_type(4))) float f32x4;
typedef __attribute__((ext_vector_type(2))) unsigned int u32x2;

__device__ inline short f2bf(float f) {
    union { float f; unsigned int u; } c; c.f = f;
    unsigned int r = (c.u + 0x7FFFu + ((c.u >> 16) & 1u)) >> 16;
    return (short)r;
}

__device__ inline float bf2f(short s) {
    union { unsigned int u; float f; } c;
    c.u = ((unsigned int)(unsigned short)s) << 16;
    return c.f;
}

__device__ inline void gload_lds16(const void* g, void* lds) {
    __builtin_amdgcn_global_load_lds(
        (const __attribute__((address_space(1))) void*)g,
        (__attribute__((address_space(3))) void*)lds, 16, 0, 0);
}

// ---------------- merged prep: weight transposes + MLP fold ----------------
// z=0: Wk->WkT[192][2560]; z=1: Wv->WvT; z=2: Wq[128][192]->WqT[192][128]
// z=3: ids 0..119 cover n=id and (id<8) n=id+120: WcatT/W2T/bfold
__global__ __launch_bounds__(320) void prep_all(
    const float* __restrict__ Wk, const float* __restrict__ Wv,
    const float* __restrict__ Wq,
    const float* __restrict__ Wo, const float* __restrict__ bo,
    const float* __restrict__ W1, const float* __restrict__ b1,
    const float* __restrict__ W2,
    short* __restrict__ WkT, short* __restrict__ WvT, short* __restrict__ WqT,
    short* __restrict__ WcatT, short* __restrict__ W2T, float* __restrict__ bfold)
{
    int z = blockIdx.z;
    int t = threadIdx.x;
    if (z < 3) {
        __shared__ float ts[64][65];
        bool act = (t < 256) && !(z == 2 && blockIdx.x >= 2);
        const float* W = (z == 0) ? Wk : (z == 1) ? Wv : Wq;
        short* WT = (z == 0) ? WkT : (z == 1) ? WvT : WqT;
        int ldk = (z == 2) ? ED : KDD;
        int k0 = blockIdx.x * 64, n0 = blockIdx.y * 64;
        if (act) {
            #pragma unroll
            for (int j = 0; j < 4; ++j) {
                int k = (t >> 4) + j * 16, n4 = (t & 15) * 4;
                float4 v = *(const float4*)&W[(size_t)(k0 + k) * DD + n0 + n4];
                ts[k][n4] = v.x; ts[k][n4 + 1] = v.y; ts[k][n4 + 2] = v.z; ts[k][n4 + 3] = v.w;
            }
        }
        __syncthreads();
        if (act) {
            int n = t >> 2, kc = (t & 3) * 16;
            short tmp[16];
            #pragma unroll
            for (int j = 0; j < 16; ++j) tmp[j] = f2bf(ts[kc + j][n]);
            *(bf16x8*)&WT[(size_t)(n0 + n) * ldk + k0 + kc] = *(bf16x8*)&tmp[0];
            *(bf16x8*)&WT[(size_t)(n0 + n) * ldk + k0 + kc + 8] = *(bf16x8*)&tmp[8];
        }
    } else {
        int id = blockIdx.y * 40 + blockIdx.x;   // 0..119
        for (int n = id; n < ED; n += 120) {     // covers n = 0..127
            int k = t;
            if (k < 128) {
                WcatT[n * 320 + k] = f2bf(W1[(size_t)k * ED + n]);
                W2T[n * 128 + k]   = f2bf(W2[(size_t)k * ED + n]);
                if (k == 0) {
                    float s = 0.f;
                    for (int j = 0; j < DD; ++j) s += bo[j] * W1[(size_t)(ED + j) * ED + n];
                    bfold[n] = s + b1[n];
                }
            } else {
                int d = k - 128;
                float s = 0.f;
                for (int j = 0; j < DD; ++j) s += Wo[(size_t)d * DD + j] * W1[(size_t)(ED + j) * ED + n];
                WcatT[n * 320 + k] = f2bf(s);
            }
        }
    }
}

// ---------------- build agg [N, 2560] bf16 + xb [N,128] bf16 ----------------
__global__ __launch_bounds__(256) void build_agg_x(
    const float* __restrict__ features, const float* __restrict__ edge_feats,
    const float* __restrict__ time_feats, const int* __restrict__ neighbors,
    const int* __restrict__ node_idx,
    short* __restrict__ agg, short* __restrict__ xb)
{
    int n = blockIdx.x;
    int col = threadIdx.x; // 0..255 == KEYD
    #pragma unroll
    for (int k = 0; k < KNB; ++k) {
        int m = neighbors[n * KNB + k];
        float v;
        if (col < ED)            v = features[m * ED + col];
        else if (col < ED + EFD) v = edge_feats[(n * KNB + k) * EFD + (col - ED)];
        else                     v = time_feats[(n * KNB + k) * TD + (col - ED - EFD)];
        agg[(size_t)n * KDD + k * KEYD + col] = f2bf(v);
    }
    if (col < ED)
        xb[n * ED + col] = f2bf(features[(size_t)node_idx[n] * ED + col]);
}

// ---------------- K/V projection (K-split x4, bf16 psum) + Q projection ----------------
// ids 0..767: kv blocks (XCD-grouped decode). ids 768..959: q blocks.
__global__ __launch_bounds__(256) void kvq_gemm_mfma(
    const short* __restrict__ agg,
    const short* __restrict__ WkT, const short* __restrict__ WvT,
    short* __restrict__ psumK, short* __restrict__ psumV,
    const short* __restrict__ xb, const short* __restrict__ WqT,
    const float* __restrict__ bq, short* __restrict__ qb)
{
    __shared__ short As[2][128 * 64];
    __shared__ short Bs[2][64 * 64];
    int tid = threadIdx.x, wid = tid >> 6, lane = tid & 63;
    int lx = lane & 15, lg = lane >> 4;
    int id = blockIdx.x;

    if (id < 768) {
        // ---- K/V projection ----
        int xcd = id & 7, slot = id >> 3;
        int g = xcd * 16 + slot / 6;
        int nb = slot % 6;
        int mb = g >> 2, s = g & 3;
        bool isV = nb >= 3;
        const short* WT = isV ? WvT : WkT;
        int n0 = (nb - (isV ? 3 : 0)) * 64;
        int m0 = mb * 128;
        int wm0 = (wid >> 1) * 64, wn0 = (wid & 1) * 32;

        f32x4 acc[4][2] = {};

        auto stage = [&](int k0, int b) {
            #pragma unroll
            for (int it = 0; it < 4; ++it) {
                int idx = (wid * 4 + it) * 64 + lane;
                int m = idx >> 3, c = (idx & 7) ^ (m & 7);
                gload_lds16(agg + (size_t)(m0 + m) * KDD + k0 + c * 8,
                            &As[b][(wid * 4 + it) * 512]);
            }
            #pragma unroll
            for (int it = 0; it < 2; ++it) {
                int idx = (wid * 2 + it) * 64 + lane;
                int n = idx >> 3, c = (idx & 7) ^ (n & 7);
                gload_lds16(WT + (size_t)(n0 + n) * KDD + k0 + c * 8,
                            &Bs[b][(wid * 2 + it) * 512]);
            }
        };

        int kbase = s * (KDD / NSPLIT);
        stage(kbase, 0);
        for (int i = 0; i < 10; ++i) {
            int b = i & 1;
            __syncthreads();
            if (i < 9) stage(kbase + (i + 1) * 64, b ^ 1);
            #pragma unroll
            for (int ks = 0; ks < 2; ++ks) {
                bf16x8 af[4], bfr[2];
                #pragma unroll
                for (int mf = 0; mf < 4; ++mf) {
                    int m = wm0 + mf * 16 + lx;
                    af[mf] = *(const bf16x8*)&As[b][m * 64 + (((ks * 4 + lg) ^ (m & 7)) << 3)];
                }
                #pragma unroll
                for (int nf = 0; nf < 2; ++nf) {
                    int n = wn0 + nf * 16 + lx;
                    bfr[nf] = *(const bf16x8*)&Bs[b][n * 64 + (((ks * 4 + lg) ^ (n & 7)) << 3)];
                }
                #pragma unroll
                for (int mf = 0; mf < 4; ++mf)
                    #pragma unroll
                    for (int nf = 0; nf < 2; ++nf)
                        acc[mf][nf] = __builtin_amdgcn_mfma_f32_16x16x32_bf16(
                            af[mf], bfr[nf], acc[mf][nf], 0, 0, 0);
            }
        }
        #pragma unroll
        for (int nf = 0; nf < 2; ++nf) {
            int ncol = n0 + wn0 + nf * 16 + lx;
            #pragma unroll
            for (int mf = 0; mf < 4; ++mf) {
                int mrow = m0 + wm0 + mf * 16 + 4 * lg;
                if (!isV) {
                    #pragma unroll
                    for (int r = 0; r < 4; ++r)
                        psumK[((size_t)s * NN + mrow + r) * DD + ncol] = f2bf(acc[mf][nf][r]);
                } else {
                    short4 s4;
                    s4.x = f2bf(acc[mf][nf][0]); s4.y = f2bf(acc[mf][nf][1]);
                    s4.z = f2bf(acc[mf][nf][2]); s4.w = f2bf(acc[mf][nf][3]);
                    *(short4*)&psumV[((size_t)(s * DD + ncol)) * NN + mrow] = s4;
                }
            }
        }
    } else {
        // ---- Q projection: qb = (x @ Wq[0:128] + bq) * scale ----
        int qid = id - 768;                 // 0..191
        int m0 = (qid / 3) * 64, n0 = (qid % 3) * 64;
        int wm0 = (wid >> 1) * 32, wn0 = (wid & 1) * 32;
        short* qAs = &As[0][0];
        short* qBs = &Bs[0][0];
        f32x4 acc[2][2] = {};

        for (int k0 = 0; k0 < ED; k0 += 64) {
            #pragma unroll
            for (int it = 0; it < 2; ++it) {
                int idx = (wid * 2 + it) * 64 + lane;
                int m = idx >> 3, c = (idx & 7) ^ (m & 7);
                gload_lds16(xb + (size_t)(m0 + m) * ED + k0 + c * 8, &qAs[(wid * 2 + it) * 512]);
            }
            #pragma unroll
            for (int it = 0; it < 2; ++it) {
                int idx = (wid * 2 + it) * 64 + lane;
                int n = idx >> 3, c = (idx & 7) ^ (n & 7);
                gload_lds16(WqT + (size_t)(n0 + n) * ED + k0 + c * 8, &qBs[(wid * 2 + it) * 512]);
            }
            __syncthreads();
            #pragma unroll
            for (int ks = 0; ks < 2; ++ks) {
                bf16x8 af[2], bfr[2];
                #pragma unroll
                for (int mf = 0; mf < 2; ++mf) {
                    int m = wm0 + mf * 16 + lx;
                    af[mf] = *(const bf16x8*)&qAs[m * 64 + (((ks * 4 + lg) ^ (m & 7)) << 3)];
                }
                #pragma unroll
                for (int nf = 0; nf < 2; ++nf) {
                    int n = wn0 + nf * 16 + lx;
                    bfr[nf] = *(const bf16x8*)&qBs[n * 64 + (((ks * 4 + lg) ^ (n & 7)) << 3)];
                }
                #pragma unroll
                for (int mf = 0; mf < 2; ++mf)
                    #pragma unroll
                    for (int nf = 0; nf < 2; ++nf)
                        acc[mf][nf] = __builtin_amdgcn_mfma_f32_16x16x32_bf16(
                            af[mf], bfr[nf], acc[mf][nf], 0, 0, 0);
            }
            __syncthreads();
        }
        const float scale = 0.10206207261596577f; // 1/sqrt(96), folded into q
        #pragma unroll
        for (int nf = 0; nf < 2; ++nf) {
            int ncol = n0 + wn0 + nf * 16 + lx;
            float bb = bq[ncol];
            #pragma unroll
            for (int mf = 0; mf < 2; ++mf) {
                int mrow = m0 + wm0 + mf * 16 + 4 * lg;
                #pragma unroll
                for (int r = 0; r < 4; ++r)
                    qb[(size_t)(mrow + r) * DD + ncol] = f2bf((acc[mf][nf][r] + bb) * scale);
            }
        }
    }
}

// ---------------- reduce K-splits (bf16 partials), add bias, cast bf16 ----------------
__global__ __launch_bounds__(256) void kv_combine(
    const short* __restrict__ psumK, const short* __restrict__ psumV,
    const float* __restrict__ bk, const float* __restrict__ bv,
    short* __restrict__ kk, short* __restrict__ vvT)
{
    const int HALF = NN * DD / 4;
    int i = blockIdx.x * 256 + threadIdx.x;
    if (i < HALF) {
        int base = i * 4, n = base % DD;
        float sum[4] = {0.f, 0.f, 0.f, 0.f};
        #pragma unroll
        for (int s = 0; s < NSPLIT; ++s) {
            short4 v = *(const short4*)&psumK[(size_t)s * NN * DD + base];
            sum[0] += bf2f(v.x); sum[1] += bf2f(v.y);
            sum[2] += bf2f(v.z); sum[3] += bf2f(v.w);
        }
        float4 bb = *(const float4*)&bk[n];
        short4 o;
        o.x = f2bf(sum[0] + bb.x); o.y = f2bf(sum[1] + bb.y);
        o.z = f2bf(sum[2] + bb.z); o.w = f2bf(sum[3] + bb.w);
        *(short4*)&kk[base] = o;
    } else {
        int j = i - HALF;
        int base = j * 4, n = base / NN;
        float sum[4] = {0.f, 0.f, 0.f, 0.f};
        #pragma unroll
        for (int s = 0; s < NSPLIT; ++s) {
            short4 v = *(const short4*)&psumV[(size_t)s * DD * NN + base];
            sum[0] += bf2f(v.x); sum[1] += bf2f(v.y);
            sum[2] += bf2f(v.z); sum[3] += bf2f(v.w);
        }
        float bb = bv[n];
        short4 o;
        o.x = f2bf(sum[0] + bb); o.y = f2bf(sum[1] + bb);
        o.z = f2bf(sum[2] + bb); o.w = f2bf(sum[3] + bb);
        *(short4*)&vvT[base] = o;
    }
}

// ---------------- flash attention, bf16 MFMA, no-max softmax ----------------
__global__ __launch_bounds__(256) void attn_mfma(
    const short* __restrict__ qb,      // [4096][192] bf16, pre-scaled
    const short* __restrict__ kk,      // [4096][192] bf16
    const short* __restrict__ vvT,     // [192][4096] bf16
    float* __restrict__ opart,         // [4][4096][192] unnormalized
    float* __restrict__ ml)            // [4][2][4096] l-sums
{
    __shared__ short Ks[2][64 * 96];
    __shared__ short Vs[2][96 * 64];
    __shared__ short Ps[4][16 * 72];
    int tid = threadIdx.x, wid = tid >> 6, lane = tid & 63;
    int lx = lane & 15, lg = lane >> 4;
    int h = blockIdx.y, split = blockIdx.z;
    int hoff = h * HD;
    int qb0 = blockIdx.x * 64 + wid * 16;

    bf16x8 qf[3];
    #pragma unroll
    for (int ks = 0; ks < 3; ++ks)
        qf[ks] = *(const bf16x8*)&qb[(size_t)(qb0 + lx) * DD + hoff + ks * 32 + lg * 8];

    auto stage = [&](int kb, int b) {
        #pragma unroll
        for (int jj = 0; jj < 6; ++jj) {
            int j = wid * 6 + jj;
            if (j < 12) {
                int idx = j * 64 + lane;
                int row = idx / 12, c = idx % 12;
                gload_lds16(kk + (size_t)(kb + row) * DD + hoff + c * 8,
                            &Ks[b][j * 512]);
            } else {
                int idx = (j - 12) * 64 + lane;
                int d = idx >> 3, c = (idx & 7) ^ (d & 7);
                gload_lds16(vvT + (size_t)(hoff + d) * NN + kb + c * 8,
                            &Vs[b][(j - 12) * 512]);
            }
        }
    };

    float lsum = 0.0f;
    f32x4 accO[6] = {};
    short* myP = &Ps[wid][0];
    int kbase = split * (NN / NSPLIT);

    stage(kbase, 0);

    for (int t = 0; t < 16; ++t) {
        int b = t & 1;
        __syncthreads();
        f32x4 sf[4];
        #pragma unroll
        for (int nf = 0; nf < 4; ++nf) sf[nf] = (f32x4){0.f, 0.f, 0.f, 0.f};
        #pragma unroll
        for (int ks = 0; ks < 3; ++ks) {
            #pragma unroll
            for (int nf = 0; nf < 4; ++nf) {
                bf16x8 kf = *(const bf16x8*)&Ks[b][(nf * 16 + lx) * 96 + ks * 32 + lg * 8];
                sf[nf] = __builtin_amdgcn_mfma_f32_16x16x32_bf16(kf, qf[ks], sf[nf], 0, 0, 0);
            }
        }
        if (t < 15) stage(kbase + (t + 1) * 64, b ^ 1);
        #pragma unroll
        for (int nf = 0; nf < 4; ++nf) {
            float p0 = __expf(sf[nf][0]);
            float p1 = __expf(sf[nf][1]);
            float p2 = __expf(sf[nf][2]);
            float p3 = __expf(sf[nf][3]);
            lsum += (p0 + p1) + (p2 + p3);
            unsigned int u0, u1;
            asm("v_cvt_pk_bf16_f32 %0, %1, %2" : "=v"(u0) : "v"(p0), "v"(p1));
            asm("v_cvt_pk_bf16_f32 %0, %1, %2" : "=v"(u1) : "v"(p2), "v"(p3));
            *(u32x2*)&myP[lx * 72 + nf * 16 + 4 * lg] = (u32x2){u0, u1};
        }
        #pragma unroll
        for (int kf2 = 0; kf2 < 2; ++kf2) {
            bf16x8 pf = *(const bf16x8*)&myP[lx * 72 + kf2 * 32 + lg * 8];
            #pragma unroll
            for (int nf2 = 0; nf2 < 6; ++nf2) {
                int d = nf2 * 16 + lx;
                bf16x8 vf = *(const bf16x8*)&Vs[b][d * 64 + (((kf2 * 4 + lg) ^ (d & 7)) << 3)];
                accO[nf2] = __builtin_amdgcn_mfma_f32_16x16x32_bf16(pf, vf, accO[nf2], 0, 0, 0);
            }
        }
    }

    float* op = opart + ((size_t)split * NN + qb0) * DD + hoff;
    #pragma unroll
    for (int nf2 = 0; nf2 < 6; ++nf2)
        #pragma unroll
        for (int r = 0; r < 4; ++r)
            op[(size_t)(4 * lg + r) * DD + nf2 * 16 + lx] = accO[nf2][r];
    lsum += __shfl_xor(lsum, 16);
    lsum += __shfl_xor(lsum, 32);
    if (lane < 16)
        ml[((size_t)(split * NH + h)) * NN + qb0 + lx] = lsum;
}

// ---------------- fused MLP: out = relu([x|ob] @ Wcat + bfold) @ W2 + b2 ----------------
// 16 rows/block, grid 256. Split-merge + normalize folded into A-staging.
__global__ __launch_bounds__(256) void mlp_fused(
    const short* __restrict__ xb,      // [4096][128] bf16
    const float* __restrict__ opart,   // [4][4096][192] fp32
    const float* __restrict__ ml,      // [4][2][4096] fp32
    const short* __restrict__ WcatT,   // [128][320] bf16
    const float* __restrict__ bfold,   // [128]
    const short* __restrict__ W2T,     // [128][128] bf16
    const float* __restrict__ b2,      // [128]
    float* __restrict__ out)           // [4096][128] fp32
{
    __shared__ short As[16 * 64];      // 2 KB
    __shared__ short Bs[128 * 64];     // 16 KB
    __shared__ short Ts[16 * 128];     // 4 KB
    __shared__ float linv[32];
    int tid = threadIdx.x, wid = tid >> 6, lane = tid & 63;
    int lx = lane & 15, lg = lane >> 4;
    int m0 = blockIdx.x * 16;
    int wn0 = wid * 32;

    if (tid < 32) {
        int rl = tid >> 1, hh = tid & 1;
        float l = 0.f;
        #pragma unroll
        for (int s = 0; s < NSPLIT; ++s) l += ml[(size_t)(s * NH + hh) * NN + m0 + rl];
        linv[tid] = 1.0f / l;
    }

    f32x4 acc[2] = {};
    for (int step = 0; step < 5; ++step) {
        int k0 = step * 64;
        if (step < 2) {
            if (wid < 2) {
                int idx = tid;             // 0..127
                int m = idx >> 3, c = (idx & 7) ^ (m & 7);
                gload_lds16(xb + (size_t)(m0 + m) * ED + k0 + c * 8, &As[wid * 512]);
            }
        } else {
            if (tid < 128) {
                int m = tid >> 3, j8 = tid & 7;
                int dg = (k0 - 128) + j8 * 8;  // global attn-dim base (head-uniform)
                float sum[8];
                float4 a0 = *(const float4*)&opart[((size_t)0 * NN + m0 + m) * DD + dg];
                float4 a1 = *(const float4*)&opart[((size_t)0 * NN + m0 + m) * DD + dg + 4];
                sum[0] = a0.x; sum[1] = a0.y; sum[2] = a0.z; sum[3] = a0.w;
                sum[4] = a1.x; sum[5] = a1.y; sum[6] = a1.z; sum[7] = a1.w;
                #pragma unroll
                for (int s = 1; s < NSPLIT; ++s) {
                    float4 b0 = *(const float4*)&opart[((size_t)s * NN + m0 + m) * DD + dg];
                    float4 b1v = *(const float4*)&opart[((size_t)s * NN + m0 + m) * DD + dg + 4];
                    sum[0] += b0.x; sum[1] += b0.y; sum[2] += b0.z; sum[3] += b0.w;
                    sum[4] += b1v.x; sum[5] += b1v.y; sum[6] += b1v.z; sum[7] += b1v.w;
                }
                float inv = linv[m * 2 + (dg >= HD ? 1 : 0)];
                short tmp[8];
                #pragma unroll
                for (int j = 0; j < 8; ++j) tmp[j] = f2bf(sum[j] * inv);
                *(bf16x8*)&As[m * 64 + ((j8 ^ (m & 7)) << 3)] = *(bf16x8*)&tmp[0];
            }
        }
        #pragma unroll
        for (int it = 0; it < 4; ++it) {
            int idx = (wid * 4 + it) * 64 + lane;
            int n = idx >> 3, c = (idx & 7) ^ (n & 7);
            gload_lds16(WcatT + (size_t)n * 320 + k0 + c * 8, &Bs[(wid * 4 + it) * 512]);
        }
        __syncthreads();
        #pragma unroll
        for (int kss = 0; kss < 2; ++kss) {
            int m = lx;
            bf16x8 af = *(const bf16x8*)&As[m * 64 + (((kss * 4 + lg) ^ (m & 7)) << 3)];
            #pragma unroll
            for (int nf = 0; nf < 2; ++nf) {
                int n = wn0 + nf * 16 + lx;
                bf16x8 bfr = *(const bf16x8*)&Bs[n * 64 + (((kss * 4 + lg) ^ (n & 7)) << 3)];
                acc[nf] = __builtin_amdgcn_mfma_f32_16x16x32_bf16(af, bfr, acc[nf], 0, 0, 0);
            }
        }
        __syncthreads();
    }
    // t = relu(acc + bfold) -> Ts swizzled
    #pragma unroll
    for (int nf = 0; nf < 2; ++nf) {
        int kcol = wn0 + nf * 16 + lx;
        float bb = bfold[kcol];
        #pragma unroll
        for (int r = 0; r < 4; ++r) {
            int m = 4 * lg + r;
            float v = fmaxf(acc[nf][r] + bb, 0.f);
            Ts[m * 128 + ((((kcol >> 3) ^ (m & 7)) << 3) | (kcol & 7))] = f2bf(v);
        }
    }
    __syncthreads();
    // out = t @ W2 + b2
    f32x4 acc2[2] = {};
    #pragma unroll
    for (int step = 0; step < 2; ++step) {
        int k0 = step * 64;
        #pragma unroll
        for (int it = 0; it < 4; ++it) {
            int idx = (wid * 4 + it) * 64 + lane;
            int n = idx >> 3, c = (idx & 7) ^ (n & 7);
            gload_lds16(W2T + (size_t)n * 128 + k0 + c * 8, &Bs[(wid * 4 + it) * 512]);
        }
        __syncthreads();
        #pragma unroll
        for (int kss = 0; kss < 2; ++kss) {
            int m = lx;
            int chunk = step * 8 + kss * 4 + lg;
            bf16x8 af = *(const bf16x8*)&Ts[m * 128 + ((chunk ^ (m & 7)) << 3)];
            #pragma unroll
            for (int nf = 0; nf < 2; ++nf) {
                int n = wn0 + nf * 16 + lx;
                bf16x8 bfr = *(const bf16x8*)&Bs[n * 64 + (((kss * 4 + lg) ^ (n & 7)) << 3)];
                acc2[nf] = __builtin_amdgcn_mfma_f32_16x16x32_bf16(af, bfr, acc2[nf], 0, 0, 0);
            }
        }
        __syncthreads();
    }
    #pragma unroll
    for (int nf = 0; nf < 2; ++nf) {
        int ncol = wn0 + nf * 16 + lx;
        float bb = b2[ncol];
        #pragma unroll
        for (int r = 0; r < 4; ++r)
            out[(size_t)(m0 + 4 * lg + r) * 128 + ncol] = acc2[nf][r] + bb;
    }
}

extern "C" void kernel_launch(void* const* d_in, const int* in_sizes, int n_in,
                              void* d_out, int out_size, void* d_ws, size_t ws_size,
                              hipStream_t stream) {
    const float* features   = (const float*)d_in[0];
    const float* edge_feats = (const float*)d_in[1];
    const float* time_feats = (const float*)d_in[2];
    const int*   neighbors  = (const int*)d_in[3];
    const int*   node_idx   = (const int*)d_in[4];
    const float* Wq = (const float*)d_in[5];
    const float* bq = (const float*)d_in[6];
    const float* Wk = (const float*)d_in[7];
    const float* bk = (const float*)d_in[8];
    const float* Wv = (const float*)d_in[9];
    const float* bv = (const float*)d_in[10];
    const float* Wo = (const float*)d_in[11];
    const float* bo = (const float*)d_in[12];
    const float* W1 = (const float*)d_in[13];
    const float* b1 = (const float*)d_in[14];
    const float* W2 = (const float*)d_in[15];
    const float* b2 = (const float*)d_in[16];
    float* out = (float*)d_out;

    char* w = (char*)d_ws;
    short* agg   = (short*)w;  w += (size_t)NN * KDD * 2;
    short* qb    = (short*)w;  w += (size_t)NN * DD * 2;
    short* kkb   = (short*)w;  w += (size_t)NN * DD * 2;
    short* vvT   = (short*)w;  w += (size_t)DD * NN * 2;
    short* WkT   = (short*)w;  w += (size_t)DD * KDD * 2;
    short* WvT   = (short*)w;  w += (size_t)DD * KDD * 2;
    short* WqT   = (short*)w;  w += (size_t)DD * ED * 2;
    short* xb    = (short*)w;  w += (size_t)NN * ED * 2;
    short* WcatT = (short*)w;  w += (size_t)ED * 320 * 2;
    short* W2T   = (short*)w;  w += (size_t)ED * ED * 2;
    float* bfold = (float*)w;  w += (size_t)ED * 4;
    // scratch region: (psumK|psumV bf16) then reused as (opart fp32|ml)
    short* psumK = (short*)w;
    short* psumV = psumK + (size_t)NSPLIT * NN * DD;
    float* opart = (float*)w;
    float* ml    = opart + (size_t)NSPLIT * NN * DD;

    prep_all<<<dim3(KDD / 64, DD / 64, 4), 320, 0, stream>>>(
        Wk, Wv, Wq, Wo, bo, W1, b1, W2, WkT, WvT, WqT, WcatT, W2T, bfold);
    build_agg_x<<<NN, 256, 0, stream>>>(features, edge_feats, time_feats,
                                        neighbors, node_idx, agg, xb);
    kvq_gemm_mfma<<<6 * (NN / 128) * NSPLIT + 192, 256, 0, stream>>>(
        agg, WkT, WvT, psumK, psumV, xb, WqT, bq, qb);
    kv_combine<<<2 * NN * DD / 4 / 256, 256, 0, stream>>>(psumK, psumV, bk, bv, kkb, vvT);
    attn_mfma<<<dim3(NN / 64, NH, NSPLIT), 256, 0, stream>>>(qb, kkb, vvT, opart, ml);
    mlp_fused<<<NN / 16, 256, 0, stream>>>(xb, opart, ml, WcatT, bfold, W2T, b2, out);
}